// Round 9
// baseline (228.213 us; speedup 1.0000x reference)
//
#include <hip/hip_runtime.h>
#include <hip/hip_bf16.h>
#include <math.h>

#define NB 512
#define NPC 32
#define KNN 12
#define NL 4
#define NN (NB*NPC)
#define WPL 28672   // prepacked bf16 weight elems per layer

typedef float v4f __attribute__((ext_vector_type(4)));
typedef short s8v __attribute__((ext_vector_type(8)));   // 16 B = 4 VGPRs

// fast silu: ~5 VALU ops (2 transcendental) vs ~10-op exact divide
__device__ __forceinline__ float silu_f(float x) {
    return x * __builtin_amdgcn_rcpf(1.0f + __builtin_amdgcn_exp2f(x * -1.44269504088896341f));
}

__device__ __forceinline__ unsigned short f2bf(float x) {
    unsigned u = __float_as_uint(x);
    u += 0x7fffu + ((u >> 16) & 1u);
    return (unsigned short)(u >> 16);
}

// packed 2xfloat -> 2xbf16 (v_cvt_pk_bf16_f32 on gfx950)
__device__ __forceinline__ unsigned pk2bf(float a, float b) {
    __hip_bfloat162 t = __float22bfloat162_rn(make_float2(a, b));
    union { __hip_bfloat162 h; unsigned u; } c; c.h = t;
    return c.u;
}

// e/12 for e<384 via magic mul (exact over [0,384))
__device__ __forceinline__ int div12(int e) { return (e * 1366) >> 14; }

// fp32 fallback GEMM (embedding only)
template<int R>
__device__ __forceinline__ void gemm_acc(const float* A, int astride,
                                         const float* __restrict__ Wg,
                                         int K, int lane, float* acc) {
#pragma unroll 2
    for (int kq = 0; kq < (K >> 2); ++kq) {
        float w0 = Wg[(4*kq+0)*64 + lane];
        float w1 = Wg[(4*kq+1)*64 + lane];
        float w2 = Wg[(4*kq+2)*64 + lane];
        float w3 = Wg[(4*kq+3)*64 + lane];
#pragma unroll
        for (int r = 0; r < R; ++r) {
            float4 a = *(const float4*)(A + r*astride + 4*kq);
            acc[r] = fmaf(a.x, w0, acc[r]);
            acc[r] = fmaf(a.y, w1, acc[r]);
            acc[r] = fmaf(a.z, w2, acc[r]);
            acc[r] = fmaf(a.w, w3, acc[r]);
        }
    }
}

// ---------------- prepack (unchanged) ----------------
extern "C" __global__ void prepack_w(const float* __restrict__ edge_w1, const float* __restrict__ edge_w2,
                                     const float* __restrict__ coord_w1, const float* __restrict__ node_w1,
                                     const float* __restrict__ node_w2, unsigned short* __restrict__ wout) {
    int g = blockIdx.x * 256 + threadIdx.x;
    if (g >= 4 * WPL / 8) return;
    int l = (g * 8) / WPL;
    int r = (g * 8) % WPL;
    int base, nKt, mat;
    if      (r < 8192)  { base = 0;     nKt = 2; mat = 0; }
    else if (r < 12288) { base = 8192;  nKt = 2; mat = 1; }
    else if (r < 16384) { base = 12288; nKt = 2; mat = 2; }
    else if (r < 24576) { base = 16384; nKt = 4; mat = 3; }
    else                { base = 24576; nKt = 2; mat = 4; }
    int idx = r - base;
    int lane = (idx >> 3) & 63, t = idx >> 9;
    int kt = t % nKt, nt = t / nKt;
    int k0 = kt*32 + ((lane >> 4) & 3)*8;
    int n  = nt*16 + (lane & 15);
    unsigned short o[8];
#pragma unroll
    for (int j = 0; j < 8; ++j) {
        int k = k0 + j;
        float v;
        if      (mat == 0) v = (n < 64) ? edge_w1[l*193*64 + k*64 + n] : edge_w1[l*193*64 + (64+k)*64 + (n-64)];
        else if (mat == 1) v = edge_w2 [l*4096 + k*64 + n];
        else if (mat == 2) v = coord_w1[l*4096 + k*64 + n];
        else if (mat == 3) v = node_w1 [l*192*64 + k*64 + n];
        else               v = node_w2 [l*4096 + k*64 + n];
        o[j] = f2bf(v);
    }
    *(s8v*)(wout + g*8) = *(s8v*)o;
}

// ---------------- main fused kernel: one block (8 waves) per crystal ----------------
// R9: (512,4) -> <=128 total regs/wave -> 2 blocks/CU (4 waves/SIMD, double
// latency hiding; R8 was reg-limited to 1 block/CU at ~>170 total). Register
// diet: w2f stays cached (static loops keep miacc in regs); wc1f point-of-use
// unroll-1 (16 regs in flight, cwp static-indexed); w1row frags reloaded per
// tile; m1 build staged in halves. WRITE_SIZE==4288KB is the no-spill check.
extern "C" __global__ __launch_bounds__(512, 4)
void crystal_fused(const float* __restrict__ z_nodes, const float* __restrict__ t_in,
                   const float* __restrict__ frac,    const float* __restrict__ lattice,
                   const float* __restrict__ time_w1, const float* __restrict__ time_b1,
                   const float* __restrict__ time_w2, const float* __restrict__ time_b2,
                   const float* __restrict__ emb_w,   const float* __restrict__ emb_b,
                   const float* __restrict__ edge_w1, const float* __restrict__ edge_b1,
                   const float* __restrict__ edge_b2, const float* __restrict__ coord_b1,
                   const float* __restrict__ coord_w2,
                   const float* __restrict__ node_w1, const float* __restrict__ node_b1,
                   const float* __restrict__ node_b2,
                   const unsigned short* __restrict__ wbf,
                   float* __restrict__ out)
{
    __shared__ __align__(16) float s_h[32*65];
    __shared__ __align__(16) unsigned short s_habf[32*136];        // bf16 [h | m_i]
    __shared__ __align__(16) unsigned short s_n1bf[32*72];
    __shared__ __align__(16) float s_hs[32*68];                    // stride 68: rows 16B-aligned
    __shared__ __align__(16) float s_hd[32*68];
    __shared__ __align__(16) unsigned short s_tiles16[8*1152];     // per-wave m2 tile; overlaid dcf/zbuf
    __shared__ float s_dsq[32][33];
    __shared__ float2 s_emeta[384];                                // {dist_sq, src bits}
    __shared__ float s_endc[384*3];
    __shared__ float s_frac[32][3];
    __shared__ float s_lat[9], s_inv[9];
    __shared__ float s_sinu[64], s_t1[128], s_tf[64];
    __shared__ float s_tb4[NL*64], s_nb4[NL*64];                   // per-layer t-terms (prologue)
    __shared__ float s_shift[32*3];

    const int tid  = threadIdx.x;
    const int c    = blockIdx.x;
    const int lane = tid & 63;
    const int wave = tid >> 6;       // 0..7
    const int q4   = lane >> 4;
    const int c16  = lane & 15;
    const int base = c * NPC;

    // ---------------- phase 0 ----------------
    if (tid < 96) {
        ((float*)s_frac)[tid] = frac[base*3 + tid];
    } else if (tid < 105) {
        s_lat[tid-96] = lattice[c*9 + (tid-96)];
    } else if (tid >= 128 && tid < 160) {
        int i = tid - 128;
        float freq = expf((float)i * (-9.210340371976184f / 31.0f));
        float ang  = t_in[c] * freq;
        s_sinu[i]    = sinf(ang);
        s_sinu[i+32] = cosf(ang);
    }
    __syncthreads();

    // ---------------- phase 1: PBC pair distances ----------------
    float* dcf = (float*)s_tiles16;      // [1024][3]
    {
        float l00=s_lat[0],l01=s_lat[1],l02=s_lat[2];
        float l10=s_lat[3],l11=s_lat[4],l12=s_lat[5];
        float l20=s_lat[6],l21=s_lat[7],l22=s_lat[8];
        for (int p = tid; p < 1024; p += 512) {
            int i = p >> 5, j = p & 31;
            float dx = s_frac[i][0]-s_frac[j][0];
            float dy = s_frac[i][1]-s_frac[j][1];
            float dz = s_frac[i][2]-s_frac[j][2];
            dx -= rintf(dx); dy -= rintf(dy); dz -= rintf(dz);
            float cx = dx*l00 + dy*l10 + dz*l20;
            float cy = dx*l01 + dy*l11 + dz*l21;
            float cz = dx*l02 + dy*l12 + dz*l22;
            float dd = cx*cx + cy*cy + cz*cz;
            s_dsq[i][j] = (i==j) ? 3.0e38f : dd;
            dcf[p*3+0]=cx; dcf[p*3+1]=cy; dcf[p*3+2]=cz;
        }
    }
    __syncthreads();

    // ---------------- phase 2: KNN (wave0 lanes<32) || time-MLP L1 ----------------
    if (tid < 32) {
        int i = tid;
        for (int k = 0; k < KNN; ++k) {
            float best = 3.9e38f; int bj = 0;
            for (int j = 0; j < 32; ++j) {
                float v = s_dsq[i][j];
                if (v < best) { best = v; bj = j; }
            }
            s_dsq[i][bj] = 3.9e38f;
            int e = i*KNN + k;
            s_emeta[e] = make_float2(best, __int_as_float(bj));
            int p = (i<<5) + bj;
            s_endc[e*3+0] = dcf[p*3+0];
            s_endc[e*3+1] = dcf[p*3+1];
            s_endc[e*3+2] = dcf[p*3+2];
        }
    } else if (tid >= 128 && tid < 256) {
        int jj = tid - 128;
        float p0 = time_b1[jj], p1=0.f, p2=0.f, p3=0.f;
        for (int k = 0; k < 64; k += 4) {
            p0 = fmaf(s_sinu[k+0], time_w1[(k+0)*128+jj], p0);
            p1 = fmaf(s_sinu[k+1], time_w1[(k+1)*128+jj], p1);
            p2 = fmaf(s_sinu[k+2], time_w1[(k+2)*128+jj], p2);
            p3 = fmaf(s_sinu[k+3], time_w1[(k+3)*128+jj], p3);
        }
        s_t1[jj] = silu_f((p0+p1) + (p2+p3));
    }
    __syncthreads();

    // ---------------- phase 3: t_feat ; zero shift ----------------
    if (tid < 64) {
        float p0=time_b2[tid],p1=0.f,p2=0.f,p3=0.f;
        for (int k = 0; k < 128; k += 4) {
            p0 = fmaf(s_t1[k+0], time_w2[(k+0)*64+tid], p0);
            p1 = fmaf(s_t1[k+1], time_w2[(k+1)*64+tid], p1);
            p2 = fmaf(s_t1[k+2], time_w2[(k+2)*64+tid], p2);
            p3 = fmaf(s_t1[k+3], time_w2[(k+3)*64+tid], p3);
        }
        s_tf[tid] = (p0+p1) + (p2+p3);
    } else if (tid < 160) {
        s_shift[tid-64] = 0.0f;
    }
    __syncthreads();

    // ---------------- phase 4: z staging + ALL-layer tb/nb GEMVs ----------------
    float* zbuf = (float*)s_tiles16;     // [32][128]
    for (int q = tid; q < 4096; q += 512) zbuf[q] = z_nodes[base*128 + q];
    {
        int l = wave >> 1, kind = wave & 1;
        const float* Wt = kind ? (node_w1 + l*192*64 + 128*64) : (edge_w1 + l*193*64 + 129*64);
        const float* bb = kind ? (node_b1 + l*64) : (edge_b1 + l*64);
        float p0 = bb[lane], p1=0.f, p2=0.f, p3=0.f;
        for (int k = 0; k < 64; k += 4) {
            p0 = fmaf(s_tf[k+0], Wt[(k+0)*64 + lane], p0);
            p1 = fmaf(s_tf[k+1], Wt[(k+1)*64 + lane], p1);
            p2 = fmaf(s_tf[k+2], Wt[(k+2)*64 + lane], p2);
            p3 = fmaf(s_tf[k+3], Wt[(k+3)*64 + lane], p3);
        }
        float v = (p0+p1) + (p2+p3);
        if (kind) s_nb4[l*64 + lane] = v;
        else      s_tb4[l*64 + lane] = v;
    }
    __syncthreads();

    // ---------------- phase 5: node embedding ----------------
    {
        float acc[4];
#pragma unroll
        for (int r = 0; r < 4; ++r) acc[r] = emb_b[lane];
        gemm_acc<4>(zbuf + (wave*4)*128, 128, emb_w, 128, lane, acc);
#pragma unroll
        for (int r = 0; r < 4; ++r) {
            int row = wave*4 + r;
            s_h[row*65 + lane] = acc[r];
            s_habf[row*136 + lane] = f2bf(acc[r]);
        }
    }
    __syncthreads();    // habf ready for layer 0 step A

    // ---------------- EGNN layers ----------------
    for (int l = 0; l < NL; ++l) {
        const unsigned short* wl = wbf + l*WPL;
        const float* w1row = edge_w1 + l*193*64 + 128*64;   // dist^2 weight row
        float b2e_v[4];
#pragma unroll
        for (int nt = 0; nt < 4; ++nt) b2e_v[nt] = edge_b2[l*64 + nt*16 + c16];
        const float cb10 = coord_b1[l*64 +  0 + c16], cb11 = coord_b1[l*64 + 16 + c16];
        const float cb12 = coord_b1[l*64 + 32 + c16], cb13 = coord_b1[l*64 + 48 + c16];
        const float w2c0 = coord_w2[l*64 +  0 + c16], w2c1 = coord_w2[l*64 + 16 + c16];
        const float w2c2 = coord_w2[l*64 + 32 + c16], w2c3 = coord_w2[l*64 + 48 + c16];

        // ---- step A: [hs|hd] = h @ [W1a|W1b] (+tb on hd) — pure MFMA+store ----
        {
            s8v a[2][2];
#pragma unroll
            for (int mt = 0; mt < 2; ++mt)
#pragma unroll
                for (int kt = 0; kt < 2; ++kt)
                    a[mt][kt] = *(const s8v*)(s_habf + (mt*16 + c16)*136 + kt*32 + q4*8);
            v4f acc[2] = {{0.f,0.f,0.f,0.f},{0.f,0.f,0.f,0.f}};
#pragma unroll
            for (int kt = 0; kt < 2; ++kt) {
                s8v b = *(const s8v*)(wl + ((wave*2+kt)*64 + lane)*8);
#pragma unroll
                for (int mt = 0; mt < 2; ++mt)
                    acc[mt] = __builtin_amdgcn_mfma_f32_16x16x32_bf16(a[mt][kt], b, acc[mt], 0, 0, 0);
            }
            int col = wave*16 + c16;
            if (wave < 4) {
#pragma unroll
                for (int mt = 0; mt < 2; ++mt)
#pragma unroll
                    for (int reg = 0; reg < 4; ++reg)
                        s_hs[(mt*16 + q4*4 + reg)*68 + col] = acc[mt][reg];
            } else {
                int colb = col - 64;
                float tbv = s_tb4[l*64 + colb];
#pragma unroll
                for (int mt = 0; mt < 2; ++mt)
#pragma unroll
                    for (int reg = 0; reg < 4; ++reg)
                        s_hd[(mt*16 + q4*4 + reg)*68 + colb] = acc[mt][reg] + tbv;
            }
        }
        __syncthreads();    // B2

        // ---- edge phase: wave owns 48 edges (dsts wave*4..+3), 3 tiles of 16 ----
        {
            s8v w2f[8];     // W2 frags cached (32 regs); static loops below keep miacc in regs
#pragma unroll
            for (int nt = 0; nt < 4; ++nt)
#pragma unroll
                for (int kt = 0; kt < 2; ++kt)
                    w2f[nt*2+kt] = *(const s8v*)(wl + 8192 + ((nt*2+kt)*64 + lane)*8);

            unsigned short* tile = s_tiles16 + wave*1152;
            float miacc[4][4];
#pragma unroll
            for (int a2 = 0; a2 < 4; ++a2)
#pragma unroll
                for (int b2 = 0; b2 < 4; ++b2) miacc[a2][b2] = 0.f;

#pragma unroll
            for (int m = 0; m < 3; ++m) {
                const int e0g = wave*48 + m*16;
                const int eL  = e0g + c16;                 // this lane's edge
                float2 me = s_emeta[eL];
                int srcn = __float_as_int(me.y);
                int dstn = div12(eL);
                float dq = me.x;
                const float* hsr = s_hs + srcn*68 + q4*8;
                const float* hdr = s_hd + dstn*68 + q4*8;
                union S8 { s8v v; unsigned u[4]; } A0, A1;
                // m1 build staged in halves (peak live ~16 regs, w1row reloaded per tile)
                {
                    float4 w0 = *(const float4*)(w1row + q4*8);
                    float4 w1 = *(const float4*)(w1row + q4*8 + 4);
                    float4 h0 = *(const float4*)(hsr);
                    float4 h1 = *(const float4*)(hsr + 4);
                    float4 g0 = *(const float4*)(hdr);
                    float4 g1 = *(const float4*)(hdr + 4);
                    A0.u[0] = pk2bf(silu_f(fmaf(dq, w0.x, h0.x + g0.x)),
                                    silu_f(fmaf(dq, w0.y, h0.y + g0.y)));
                    A0.u[1] = pk2bf(silu_f(fmaf(dq, w0.z, h0.z + g0.z)),
                                    silu_f(fmaf(dq, w0.w, h0.w + g0.w)));
                    A0.u[2] = pk2bf(silu_f(fmaf(dq, w1.x, h1.x + g1.x)),
                                    silu_f(fmaf(dq, w1.y, h1.y + g1.y)));
                    A0.u[3] = pk2bf(silu_f(fmaf(dq, w1.z, h1.z + g1.z)),
                                    silu_f(fmaf(dq, w1.w, h1.w + g1.w)));
                }
                {
                    float4 w2 = *(const float4*)(w1row + 32 + q4*8);
                    float4 w3 = *(const float4*)(w1row + 32 + q4*8 + 4);
                    float4 h2 = *(const float4*)(hsr + 32);
                    float4 h3 = *(const float4*)(hsr + 36);
                    float4 g2 = *(const float4*)(hdr + 32);
                    float4 g3 = *(const float4*)(hdr + 36);
                    A1.u[0] = pk2bf(silu_f(fmaf(dq, w2.x, h2.x + g2.x)),
                                    silu_f(fmaf(dq, w2.y, h2.y + g2.y)));
                    A1.u[1] = pk2bf(silu_f(fmaf(dq, w2.z, h2.z + g2.z)),
                                    silu_f(fmaf(dq, w2.w, h2.w + g2.w)));
                    A1.u[2] = pk2bf(silu_f(fmaf(dq, w3.x, h3.x + g3.x)),
                                    silu_f(fmaf(dq, w3.y, h3.y + g3.y)));
                    A1.u[3] = pk2bf(silu_f(fmaf(dq, w3.z, h3.z + g3.z)),
                                    silu_f(fmaf(dq, w3.w, h3.w + g3.w)));
                }

                // m2 = silu(m1@W2 + b2): fully unrolled, cached w2f; mi in regs
                const int thr = (m==0) ? 3 : (m==1) ? 2 : 1;   // q4>=thr -> second dst
                const int dlo = m;                              // local dst ids {m, m+1}
#pragma unroll
                for (int nt = 0; nt < 4; ++nt) {
                    v4f acc = {0.f,0.f,0.f,0.f};
                    acc = __builtin_amdgcn_mfma_f32_16x16x32_bf16(A0.v, w2f[nt*2+0], acc, 0,0,0);
                    acc = __builtin_amdgcn_mfma_f32_16x16x32_bf16(A1.v, w2f[nt*2+1], acc, 0,0,0);
                    int col = nt*16 + c16;
                    float msum = 0.f;
#pragma unroll
                    for (int reg = 0; reg < 4; ++reg) {
                        float v = silu_f(acc[reg] + b2e_v[nt]);
                        tile[(q4*4 + reg)*72 + col] = f2bf(v);
                        msum += v;
                    }
                    bool hi = (q4 >= thr);
                    miacc[nt][dlo]   += hi ? 0.f : msum;
                    miacc[nt][dlo+1] += hi ? msum : 0.f;
                }
                asm volatile("s_waitcnt lgkmcnt(0)" ::: "memory");
                s8v c0 = *(const s8v*)(tile + c16*72 +      q4*8);
                s8v c1 = *(const s8v*)(tile + c16*72 + 32 + q4*8);
                // cw = silu(m2@Wc1 + cb1) . w2c — point-of-use Wc1, unroll-1 (16 regs inflight)
                float cwp[4] = {0.f,0.f,0.f,0.f};
#pragma unroll 1
                for (int nt = 0; nt < 4; ++nt) {
                    s8v b0 = *(const s8v*)(wl + 12288 + ((nt*2+0)*64 + lane)*8);
                    s8v b1 = *(const s8v*)(wl + 12288 + ((nt*2+1)*64 + lane)*8);
                    v4f acc = {0.f,0.f,0.f,0.f};
                    acc = __builtin_amdgcn_mfma_f32_16x16x32_bf16(c0, b0, acc, 0,0,0);
                    acc = __builtin_amdgcn_mfma_f32_16x16x32_bf16(c1, b1, acc, 0,0,0);
                    float cb1 = (nt==0) ? cb10 : (nt==1) ? cb11 : (nt==2) ? cb12 : cb13;
                    float w2c = (nt==0) ? w2c0 : (nt==1) ? w2c1 : (nt==2) ? w2c2 : w2c3;
#pragma unroll
                    for (int reg = 0; reg < 4; ++reg)
                        cwp[reg] += silu_f(acc[reg] + cb1) * w2c;
                }
#pragma unroll
                for (int reg = 0; reg < 4; ++reg) {
                    float v = cwp[reg];
                    v += __shfl_xor(v, 1); v += __shfl_xor(v, 2);
                    v += __shfl_xor(v, 4); v += __shfl_xor(v, 8);
                    int e = e0g + q4*4 + reg;
                    if (c16 < 3) {
                        int src = __float_as_int(s_emeta[e].y);
                        atomicAdd(&s_shift[src*3 + c16], s_endc[e*3 + c16] * v);
                    }
                }
            }
            // mi: reduce across q4 groups, write bf16 into habf cols 64..127
#pragma unroll
            for (int nt = 0; nt < 4; ++nt)
#pragma unroll
                for (int d = 0; d < 4; ++d) {
                    float v = miacc[nt][d];
                    v += __shfl_xor(v, 16);
                    v += __shfl_xor(v, 32);
                    s_habf[(wave*4 + d)*136 + 64 + nt*16 + c16] = f2bf(v);
                }
        }
        __syncthreads();    // B3

        // ---- node GEMM1: wave -> (mt = w&1, nt = w>>1) sub-tile ----
        {
            int mt = wave & 1, nt = wave >> 1;
            int col = nt*16 + c16;
            float nbc = s_nb4[l*64 + col];
            v4f acc = {0.f,0.f,0.f,0.f};
#pragma unroll
            for (int kt = 0; kt < 4; ++kt) {
                s8v b = *(const s8v*)(wl + 16384 + ((nt*4+kt)*64 + lane)*8);
                s8v a = *(const s8v*)(s_habf + (mt*16 + c16)*136 + kt*32 + q4*8);
                acc = __builtin_amdgcn_mfma_f32_16x16x32_bf16(a, b, acc, 0,0,0);
            }
#pragma unroll
            for (int reg = 0; reg < 4; ++reg) {
                int row = mt*16 + q4*4 + reg;
                s_n1bf[row*72 + col] = f2bf(silu_f(acc[reg] + nbc));
            }
        }
        __syncthreads();    // B4

        // ---- node GEMM2: h += n1@Wn2 + b2 ----
        {
            int mt = wave & 1, nt = wave >> 1;
            s8v b0 = *(const s8v*)(wl + 24576 + ((nt*2+0)*64 + lane)*8);
            s8v b1 = *(const s8v*)(wl + 24576 + ((nt*2+1)*64 + lane)*8);
            int col = nt*16 + c16;
            float nb2_v = node_b2[l*64 + col];
            s8v a0 = *(const s8v*)(s_n1bf + (mt*16 + c16)*72 +      q4*8);
            s8v a1 = *(const s8v*)(s_n1bf + (mt*16 + c16)*72 + 32 + q4*8);
            v4f acc = {0.f,0.f,0.f,0.f};
            acc = __builtin_amdgcn_mfma_f32_16x16x32_bf16(a0, b0, acc, 0,0,0);
            acc = __builtin_amdgcn_mfma_f32_16x16x32_bf16(a1, b1, acc, 0,0,0);
#pragma unroll
            for (int reg = 0; reg < 4; ++reg) {
                int row = mt*16 + q4*4 + reg;
                float hn = s_h[row*65 + col] + acc[reg] + nb2_v;
                s_h[row*65 + col] = hn;
                s_habf[row*136 + col] = f2bf(hn);
            }
        }
        __syncthreads();    // B5
    }

    // ---------------- epilogue ----------------
    if (tid == 0) {
        float a=s_lat[0],b=s_lat[1],cc=s_lat[2];
        float d=s_lat[3],e=s_lat[4],f =s_lat[5];
        float g=s_lat[6],h2=s_lat[7],i2=s_lat[8];
        float A  =  (e*i2 - f*h2);
        float Bm = -(d*i2 - f*g);
        float C  =  (d*h2 - e*g);
        float det = a*A + b*Bm + cc*C;
        float rd = 1.0f/det;
        s_inv[0] = A*rd;
        s_inv[1] = -(b*i2 - cc*h2)*rd;
        s_inv[2] =  (b*f  - cc*e )*rd;
        s_inv[3] = Bm*rd;
        s_inv[4] =  (a*i2 - cc*g )*rd;
        s_inv[5] = -(a*f  - cc*d )*rd;
        s_inv[6] = C*rd;
        s_inv[7] = -(a*h2 - b*g  )*rd;
        s_inv[8] =  (a*e  - b*d  )*rd;
    }
    __syncthreads();
    if (tid < 96) {
        int r = tid/3, j = tid%3;
        float v = s_shift[r*3+0]*s_inv[0*3+j]
                + s_shift[r*3+1]*s_inv[1*3+j]
                + s_shift[r*3+2]*s_inv[2*3+j];
        out[(base + r)*3 + j] = v;
    }
    for (int q = tid; q < 2048; q += 512) {
        int row = q >> 6, colq = q & 63;
        out[NN*3 + base*64 + q] = s_h[row*65 + colq];
    }
}

extern "C" void kernel_launch(void* const* d_in, const int* in_sizes, int n_in,
                              void* d_out, int out_size, void* d_ws, size_t ws_size,
                              hipStream_t stream) {
    unsigned short* wbf = (unsigned short*)d_ws;
    prepack_w<<<(4*WPL/8 + 255)/256, 256, 0, stream>>>(
        (const float*)d_in[12], (const float*)d_in[14], (const float*)d_in[16],
        (const float*)d_in[19], (const float*)d_in[21], wbf);
    crystal_fused<<<NB, 512, 0, stream>>>(
        (const float*)d_in[0],  (const float*)d_in[1],  (const float*)d_in[2],  (const float*)d_in[3],
        (const float*)d_in[6],  (const float*)d_in[7],  (const float*)d_in[8],  (const float*)d_in[9],
        (const float*)d_in[10], (const float*)d_in[11],
        (const float*)d_in[12], (const float*)d_in[13], (const float*)d_in[15],
        (const float*)d_in[17], (const float*)d_in[18],
        (const float*)d_in[19], (const float*)d_in[20], (const float*)d_in[22],
        wbf, (float*)d_out);
}

// Round 10
// 226.917 us; speedup vs baseline: 1.0057x; 1.0057x over previous
//
#include <hip/hip_runtime.h>
#include <hip/hip_bf16.h>
#include <math.h>

#define NB 512
#define NPC 32
#define KNN 12
#define NL 4
#define NN (NB*NPC)
#define WPL 28672   // prepacked bf16 weight elems per layer

typedef float v4f __attribute__((ext_vector_type(4)));
typedef short s8v __attribute__((ext_vector_type(8)));   // 16 B = 4 VGPRs

// scheduling fence: no instruction emitted; memory ops cannot cross.
// Bounds register liveness by stopping cross-tile load hoisting (R9 spill cause).
#define SCHED_FENCE() asm volatile("" ::: "memory")

// fast silu: ~5 VALU ops (2 transcendental) vs ~10-op exact divide
__device__ __forceinline__ float silu_f(float x) {
    return x * __builtin_amdgcn_rcpf(1.0f + __builtin_amdgcn_exp2f(x * -1.44269504088896341f));
}

__device__ __forceinline__ unsigned short f2bf(float x) {
    unsigned u = __float_as_uint(x);
    u += 0x7fffu + ((u >> 16) & 1u);
    return (unsigned short)(u >> 16);
}

// packed 2xfloat -> 2xbf16 (v_cvt_pk_bf16_f32 on gfx950)
__device__ __forceinline__ unsigned pk2bf(float a, float b) {
    __hip_bfloat162 t = __float22bfloat162_rn(make_float2(a, b));
    union { __hip_bfloat162 h; unsigned u; } c; c.h = t;
    return c.u;
}

// e/12 for e<384 via magic mul (exact over [0,384))
__device__ __forceinline__ int div12(int e) { return (e * 1366) >> 14; }

// fp32 fallback GEMM (embedding only)
template<int R>
__device__ __forceinline__ void gemm_acc(const float* A, int astride,
                                         const float* __restrict__ Wg,
                                         int K, int lane, float* acc) {
#pragma unroll 2
    for (int kq = 0; kq < (K >> 2); ++kq) {
        float w0 = Wg[(4*kq+0)*64 + lane];
        float w1 = Wg[(4*kq+1)*64 + lane];
        float w2 = Wg[(4*kq+2)*64 + lane];
        float w3 = Wg[(4*kq+3)*64 + lane];
#pragma unroll
        for (int r = 0; r < R; ++r) {
            float4 a = *(const float4*)(A + r*astride + 4*kq);
            acc[r] = fmaf(a.x, w0, acc[r]);
            acc[r] = fmaf(a.y, w1, acc[r]);
            acc[r] = fmaf(a.z, w2, acc[r]);
            acc[r] = fmaf(a.w, w3, acc[r]);
        }
    }
}

// ---------------- prepack (unchanged) ----------------
extern "C" __global__ void prepack_w(const float* __restrict__ edge_w1, const float* __restrict__ edge_w2,
                                     const float* __restrict__ coord_w1, const float* __restrict__ node_w1,
                                     const float* __restrict__ node_w2, unsigned short* __restrict__ wout) {
    int g = blockIdx.x * 256 + threadIdx.x;
    if (g >= 4 * WPL / 8) return;
    int l = (g * 8) / WPL;
    int r = (g * 8) % WPL;
    int base, nKt, mat;
    if      (r < 8192)  { base = 0;     nKt = 2; mat = 0; }
    else if (r < 12288) { base = 8192;  nKt = 2; mat = 1; }
    else if (r < 16384) { base = 12288; nKt = 2; mat = 2; }
    else if (r < 24576) { base = 16384; nKt = 4; mat = 3; }
    else                { base = 24576; nKt = 2; mat = 4; }
    int idx = r - base;
    int lane = (idx >> 3) & 63, t = idx >> 9;
    int kt = t % nKt, nt = t / nKt;
    int k0 = kt*32 + ((lane >> 4) & 3)*8;
    int n  = nt*16 + (lane & 15);
    unsigned short o[8];
#pragma unroll
    for (int j = 0; j < 8; ++j) {
        int k = k0 + j;
        float v;
        if      (mat == 0) v = (n < 64) ? edge_w1[l*193*64 + k*64 + n] : edge_w1[l*193*64 + (64+k)*64 + (n-64)];
        else if (mat == 1) v = edge_w2 [l*4096 + k*64 + n];
        else if (mat == 2) v = coord_w1[l*4096 + k*64 + n];
        else if (mat == 3) v = node_w1 [l*192*64 + k*64 + n];
        else               v = node_w2 [l*4096 + k*64 + n];
        o[j] = f2bf(v);
    }
    *(s8v*)(wout + g*8) = *(s8v*)o;
}

// ---------------- main fused kernel: one block (8 waves) per crystal ----------------
// R10: R9 structure (512,4 / 2 blocks/CU) + SCHED_FENCE at m-tile boundaries.
// R9 spilled (~100MB scratch) because full unroll let LLVM hoist next tiles'
// w1row/hs/hd loads across tile boundaries (~48+ extra live regs). Fences pin
// loads inside their tile; static count ~95 regs fits the 128 cap.
extern "C" __global__ __launch_bounds__(512, 4)
void crystal_fused(const float* __restrict__ z_nodes, const float* __restrict__ t_in,
                   const float* __restrict__ frac,    const float* __restrict__ lattice,
                   const float* __restrict__ time_w1, const float* __restrict__ time_b1,
                   const float* __restrict__ time_w2, const float* __restrict__ time_b2,
                   const float* __restrict__ emb_w,   const float* __restrict__ emb_b,
                   const float* __restrict__ edge_w1, const float* __restrict__ edge_b1,
                   const float* __restrict__ edge_b2, const float* __restrict__ coord_b1,
                   const float* __restrict__ coord_w2,
                   const float* __restrict__ node_w1, const float* __restrict__ node_b1,
                   const float* __restrict__ node_b2,
                   const unsigned short* __restrict__ wbf,
                   float* __restrict__ out)
{
    __shared__ __align__(16) float s_h[32*65];
    __shared__ __align__(16) unsigned short s_habf[32*136];        // bf16 [h | m_i]
    __shared__ __align__(16) unsigned short s_n1bf[32*72];
    __shared__ __align__(16) float s_hs[32*68];                    // stride 68: rows 16B-aligned
    __shared__ __align__(16) float s_hd[32*68];
    __shared__ __align__(16) unsigned short s_tiles16[8*1152];     // per-wave m2 tile; overlaid dcf/zbuf
    __shared__ float s_dsq[32][33];
    __shared__ float2 s_emeta[384];                                // {dist_sq, src bits}
    __shared__ float s_endc[384*3];
    __shared__ float s_frac[32][3];
    __shared__ float s_lat[9], s_inv[9];
    __shared__ float s_sinu[64], s_t1[128], s_tf[64];
    __shared__ float s_tb4[NL*64], s_nb4[NL*64];                   // per-layer t-terms (prologue)
    __shared__ float s_shift[32*3];

    const int tid  = threadIdx.x;
    const int c    = blockIdx.x;
    const int lane = tid & 63;
    const int wave = tid >> 6;       // 0..7
    const int q4   = lane >> 4;
    const int c16  = lane & 15;
    const int base = c * NPC;

    // ---------------- phase 0 ----------------
    if (tid < 96) {
        ((float*)s_frac)[tid] = frac[base*3 + tid];
    } else if (tid < 105) {
        s_lat[tid-96] = lattice[c*9 + (tid-96)];
    } else if (tid >= 128 && tid < 160) {
        int i = tid - 128;
        float freq = expf((float)i * (-9.210340371976184f / 31.0f));
        float ang  = t_in[c] * freq;
        s_sinu[i]    = sinf(ang);
        s_sinu[i+32] = cosf(ang);
    }
    __syncthreads();

    // ---------------- phase 1: PBC pair distances ----------------
    float* dcf = (float*)s_tiles16;      // [1024][3]
    {
        float l00=s_lat[0],l01=s_lat[1],l02=s_lat[2];
        float l10=s_lat[3],l11=s_lat[4],l12=s_lat[5];
        float l20=s_lat[6],l21=s_lat[7],l22=s_lat[8];
        for (int p = tid; p < 1024; p += 512) {
            int i = p >> 5, j = p & 31;
            float dx = s_frac[i][0]-s_frac[j][0];
            float dy = s_frac[i][1]-s_frac[j][1];
            float dz = s_frac[i][2]-s_frac[j][2];
            dx -= rintf(dx); dy -= rintf(dy); dz -= rintf(dz);
            float cx = dx*l00 + dy*l10 + dz*l20;
            float cy = dx*l01 + dy*l11 + dz*l21;
            float cz = dx*l02 + dy*l12 + dz*l22;
            float dd = cx*cx + cy*cy + cz*cz;
            s_dsq[i][j] = (i==j) ? 3.0e38f : dd;
            dcf[p*3+0]=cx; dcf[p*3+1]=cy; dcf[p*3+2]=cz;
        }
    }
    __syncthreads();

    // ---------------- phase 2: KNN (wave0 lanes<32) || time-MLP L1 ----------------
    if (tid < 32) {
        int i = tid;
        for (int k = 0; k < KNN; ++k) {
            float best = 3.9e38f; int bj = 0;
            for (int j = 0; j < 32; ++j) {
                float v = s_dsq[i][j];
                if (v < best) { best = v; bj = j; }
            }
            s_dsq[i][bj] = 3.9e38f;
            int e = i*KNN + k;
            s_emeta[e] = make_float2(best, __int_as_float(bj));
            int p = (i<<5) + bj;
            s_endc[e*3+0] = dcf[p*3+0];
            s_endc[e*3+1] = dcf[p*3+1];
            s_endc[e*3+2] = dcf[p*3+2];
        }
    } else if (tid >= 128 && tid < 256) {
        int jj = tid - 128;
        float p0 = time_b1[jj], p1=0.f, p2=0.f, p3=0.f;
        for (int k = 0; k < 64; k += 4) {
            p0 = fmaf(s_sinu[k+0], time_w1[(k+0)*128+jj], p0);
            p1 = fmaf(s_sinu[k+1], time_w1[(k+1)*128+jj], p1);
            p2 = fmaf(s_sinu[k+2], time_w1[(k+2)*128+jj], p2);
            p3 = fmaf(s_sinu[k+3], time_w1[(k+3)*128+jj], p3);
        }
        s_t1[jj] = silu_f((p0+p1) + (p2+p3));
    }
    __syncthreads();

    // ---------------- phase 3: t_feat ; zero shift ----------------
    if (tid < 64) {
        float p0=time_b2[tid],p1=0.f,p2=0.f,p3=0.f;
        for (int k = 0; k < 128; k += 4) {
            p0 = fmaf(s_t1[k+0], time_w2[(k+0)*64+tid], p0);
            p1 = fmaf(s_t1[k+1], time_w2[(k+1)*64+tid], p1);
            p2 = fmaf(s_t1[k+2], time_w2[(k+2)*64+tid], p2);
            p3 = fmaf(s_t1[k+3], time_w2[(k+3)*64+tid], p3);
        }
        s_tf[tid] = (p0+p1) + (p2+p3);
    } else if (tid < 160) {
        s_shift[tid-64] = 0.0f;
    }
    __syncthreads();

    // ---------------- phase 4: z staging + ALL-layer tb/nb GEMVs ----------------
    float* zbuf = (float*)s_tiles16;     // [32][128]
    for (int q = tid; q < 4096; q += 512) zbuf[q] = z_nodes[base*128 + q];
    {
        int l = wave >> 1, kind = wave & 1;
        const float* Wt = kind ? (node_w1 + l*192*64 + 128*64) : (edge_w1 + l*193*64 + 129*64);
        const float* bb = kind ? (node_b1 + l*64) : (edge_b1 + l*64);
        float p0 = bb[lane], p1=0.f, p2=0.f, p3=0.f;
        for (int k = 0; k < 64; k += 4) {
            p0 = fmaf(s_tf[k+0], Wt[(k+0)*64 + lane], p0);
            p1 = fmaf(s_tf[k+1], Wt[(k+1)*64 + lane], p1);
            p2 = fmaf(s_tf[k+2], Wt[(k+2)*64 + lane], p2);
            p3 = fmaf(s_tf[k+3], Wt[(k+3)*64 + lane], p3);
        }
        float v = (p0+p1) + (p2+p3);
        if (kind) s_nb4[l*64 + lane] = v;
        else      s_tb4[l*64 + lane] = v;
    }
    __syncthreads();

    // ---------------- phase 5: node embedding ----------------
    {
        float acc[4];
#pragma unroll
        for (int r = 0; r < 4; ++r) acc[r] = emb_b[lane];
        gemm_acc<4>(zbuf + (wave*4)*128, 128, emb_w, 128, lane, acc);
#pragma unroll
        for (int r = 0; r < 4; ++r) {
            int row = wave*4 + r;
            s_h[row*65 + lane] = acc[r];
            s_habf[row*136 + lane] = f2bf(acc[r]);
        }
    }
    __syncthreads();    // habf ready for layer 0 step A

    // ---------------- EGNN layers ----------------
    for (int l = 0; l < NL; ++l) {
        const unsigned short* wl = wbf + l*WPL;
        const float* w1row = edge_w1 + l*193*64 + 128*64;   // dist^2 weight row
        float b2e_v[4];
#pragma unroll
        for (int nt = 0; nt < 4; ++nt) b2e_v[nt] = edge_b2[l*64 + nt*16 + c16];
        const float cb10 = coord_b1[l*64 +  0 + c16], cb11 = coord_b1[l*64 + 16 + c16];
        const float cb12 = coord_b1[l*64 + 32 + c16], cb13 = coord_b1[l*64 + 48 + c16];
        const float w2c0 = coord_w2[l*64 +  0 + c16], w2c1 = coord_w2[l*64 + 16 + c16];
        const float w2c2 = coord_w2[l*64 + 32 + c16], w2c3 = coord_w2[l*64 + 48 + c16];

        // ---- step A: [hs|hd] = h @ [W1a|W1b] (+tb on hd) — pure MFMA+store ----
        {
            s8v a[2][2];
#pragma unroll
            for (int mt = 0; mt < 2; ++mt)
#pragma unroll
                for (int kt = 0; kt < 2; ++kt)
                    a[mt][kt] = *(const s8v*)(s_habf + (mt*16 + c16)*136 + kt*32 + q4*8);
            v4f acc[2] = {{0.f,0.f,0.f,0.f},{0.f,0.f,0.f,0.f}};
#pragma unroll
            for (int kt = 0; kt < 2; ++kt) {
                s8v b = *(const s8v*)(wl + ((wave*2+kt)*64 + lane)*8);
#pragma unroll
                for (int mt = 0; mt < 2; ++mt)
                    acc[mt] = __builtin_amdgcn_mfma_f32_16x16x32_bf16(a[mt][kt], b, acc[mt], 0, 0, 0);
            }
            int col = wave*16 + c16;
            if (wave < 4) {
#pragma unroll
                for (int mt = 0; mt < 2; ++mt)
#pragma unroll
                    for (int reg = 0; reg < 4; ++reg)
                        s_hs[(mt*16 + q4*4 + reg)*68 + col] = acc[mt][reg];
            } else {
                int colb = col - 64;
                float tbv = s_tb4[l*64 + colb];
#pragma unroll
                for (int mt = 0; mt < 2; ++mt)
#pragma unroll
                    for (int reg = 0; reg < 4; ++reg)
                        s_hd[(mt*16 + q4*4 + reg)*68 + colb] = acc[mt][reg] + tbv;
            }
        }
        __syncthreads();    // B2

        // ---- edge phase: wave owns 48 edges (dsts wave*4..+3), 3 tiles of 16 ----
        {
            s8v w2f[8];     // W2 frags cached (32 regs); static loops below keep miacc in regs
#pragma unroll
            for (int nt = 0; nt < 4; ++nt)
#pragma unroll
                for (int kt = 0; kt < 2; ++kt)
                    w2f[nt*2+kt] = *(const s8v*)(wl + 8192 + ((nt*2+kt)*64 + lane)*8);

            unsigned short* tile = s_tiles16 + wave*1152;
            float miacc[4][4];
#pragma unroll
            for (int a2 = 0; a2 < 4; ++a2)
#pragma unroll
                for (int b2 = 0; b2 < 4; ++b2) miacc[a2][b2] = 0.f;

#pragma unroll
            for (int m = 0; m < 3; ++m) {
                SCHED_FENCE();   // pin this tile's loads inside the tile (R9 spill fix)
                const int e0g = wave*48 + m*16;
                const int eL  = e0g + c16;                 // this lane's edge
                float2 me = s_emeta[eL];
                int srcn = __float_as_int(me.y);
                int dstn = div12(eL);
                float dq = me.x;
                const float* hsr = s_hs + srcn*68 + q4*8;
                const float* hdr = s_hd + dstn*68 + q4*8;
                union S8 { s8v v; unsigned u[4]; } A0, A1;
                // m1 build staged in halves (peak live ~16 regs)
                {
                    float4 w0 = *(const float4*)(w1row + q4*8);
                    float4 w1 = *(const float4*)(w1row + q4*8 + 4);
                    float4 h0 = *(const float4*)(hsr);
                    float4 h1 = *(const float4*)(hsr + 4);
                    float4 g0 = *(const float4*)(hdr);
                    float4 g1 = *(const float4*)(hdr + 4);
                    A0.u[0] = pk2bf(silu_f(fmaf(dq, w0.x, h0.x + g0.x)),
                                    silu_f(fmaf(dq, w0.y, h0.y + g0.y)));
                    A0.u[1] = pk2bf(silu_f(fmaf(dq, w0.z, h0.z + g0.z)),
                                    silu_f(fmaf(dq, w0.w, h0.w + g0.w)));
                    A0.u[2] = pk2bf(silu_f(fmaf(dq, w1.x, h1.x + g1.x)),
                                    silu_f(fmaf(dq, w1.y, h1.y + g1.y)));
                    A0.u[3] = pk2bf(silu_f(fmaf(dq, w1.z, h1.z + g1.z)),
                                    silu_f(fmaf(dq, w1.w, h1.w + g1.w)));
                }
                {
                    float4 w2 = *(const float4*)(w1row + 32 + q4*8);
                    float4 w3 = *(const float4*)(w1row + 32 + q4*8 + 4);
                    float4 h2 = *(const float4*)(hsr + 32);
                    float4 h3 = *(const float4*)(hsr + 36);
                    float4 g2 = *(const float4*)(hdr + 32);
                    float4 g3 = *(const float4*)(hdr + 36);
                    A1.u[0] = pk2bf(silu_f(fmaf(dq, w2.x, h2.x + g2.x)),
                                    silu_f(fmaf(dq, w2.y, h2.y + g2.y)));
                    A1.u[1] = pk2bf(silu_f(fmaf(dq, w2.z, h2.z + g2.z)),
                                    silu_f(fmaf(dq, w2.w, h2.w + g2.w)));
                    A1.u[2] = pk2bf(silu_f(fmaf(dq, w3.x, h3.x + g3.x)),
                                    silu_f(fmaf(dq, w3.y, h3.y + g3.y)));
                    A1.u[3] = pk2bf(silu_f(fmaf(dq, w3.z, h3.z + g3.z)),
                                    silu_f(fmaf(dq, w3.w, h3.w + g3.w)));
                }

                // m2 = silu(m1@W2 + b2): fully unrolled, cached w2f; mi in regs
                const int thr = (m==0) ? 3 : (m==1) ? 2 : 1;   // q4>=thr -> second dst
                const int dlo = m;                              // local dst ids {m, m+1}
#pragma unroll
                for (int nt = 0; nt < 4; ++nt) {
                    v4f acc = {0.f,0.f,0.f,0.f};
                    acc = __builtin_amdgcn_mfma_f32_16x16x32_bf16(A0.v, w2f[nt*2+0], acc, 0,0,0);
                    acc = __builtin_amdgcn_mfma_f32_16x16x32_bf16(A1.v, w2f[nt*2+1], acc, 0,0,0);
                    int col = nt*16 + c16;
                    float msum = 0.f;
#pragma unroll
                    for (int reg = 0; reg < 4; ++reg) {
                        float v = silu_f(acc[reg] + b2e_v[nt]);
                        tile[(q4*4 + reg)*72 + col] = f2bf(v);
                        msum += v;
                    }
                    bool hi = (q4 >= thr);
                    miacc[nt][dlo]   += hi ? 0.f : msum;
                    miacc[nt][dlo+1] += hi ? msum : 0.f;
                }
                asm volatile("s_waitcnt lgkmcnt(0)" ::: "memory");
                s8v c0 = *(const s8v*)(tile + c16*72 +      q4*8);
                s8v c1 = *(const s8v*)(tile + c16*72 + 32 + q4*8);
                // cw = silu(m2@Wc1 + cb1) . w2c — point-of-use Wc1, unroll-1 (16 regs inflight)
                float cwp[4] = {0.f,0.f,0.f,0.f};
#pragma unroll 1
                for (int nt = 0; nt < 4; ++nt) {
                    s8v b0 = *(const s8v*)(wl + 12288 + ((nt*2+0)*64 + lane)*8);
                    s8v b1 = *(const s8v*)(wl + 12288 + ((nt*2+1)*64 + lane)*8);
                    v4f acc = {0.f,0.f,0.f,0.f};
                    acc = __builtin_amdgcn_mfma_f32_16x16x32_bf16(c0, b0, acc, 0,0,0);
                    acc = __builtin_amdgcn_mfma_f32_16x16x32_bf16(c1, b1, acc, 0,0,0);
                    float cb1 = (nt==0) ? cb10 : (nt==1) ? cb11 : (nt==2) ? cb12 : cb13;
                    float w2c = (nt==0) ? w2c0 : (nt==1) ? w2c1 : (nt==2) ? w2c2 : w2c3;
#pragma unroll
                    for (int reg = 0; reg < 4; ++reg)
                        cwp[reg] += silu_f(acc[reg] + cb1) * w2c;
                }
#pragma unroll
                for (int reg = 0; reg < 4; ++reg) {
                    float v = cwp[reg];
                    v += __shfl_xor(v, 1); v += __shfl_xor(v, 2);
                    v += __shfl_xor(v, 4); v += __shfl_xor(v, 8);
                    int e = e0g + q4*4 + reg;
                    if (c16 < 3) {
                        int src = __float_as_int(s_emeta[e].y);
                        atomicAdd(&s_shift[src*3 + c16], s_endc[e*3 + c16] * v);
                    }
                }
                SCHED_FENCE();   // close the tile's liveness window
            }
            // mi: reduce across q4 groups, write bf16 into habf cols 64..127
#pragma unroll
            for (int nt = 0; nt < 4; ++nt)
#pragma unroll
                for (int d = 0; d < 4; ++d) {
                    float v = miacc[nt][d];
                    v += __shfl_xor(v, 16);
                    v += __shfl_xor(v, 32);
                    s_habf[(wave*4 + d)*136 + 64 + nt*16 + c16] = f2bf(v);
                }
        }
        __syncthreads();    // B3

        // ---- node GEMM1: wave -> (mt = w&1, nt = w>>1) sub-tile ----
        {
            int mt = wave & 1, nt = wave >> 1;
            int col = nt*16 + c16;
            float nbc = s_nb4[l*64 + col];
            v4f acc = {0.f,0.f,0.f,0.f};
#pragma unroll
            for (int kt = 0; kt < 4; ++kt) {
                s8v b = *(const s8v*)(wl + 16384 + ((nt*4+kt)*64 + lane)*8);
                s8v a = *(const s8v*)(s_habf + (mt*16 + c16)*136 + kt*32 + q4*8);
                acc = __builtin_amdgcn_mfma_f32_16x16x32_bf16(a, b, acc, 0,0,0);
            }
#pragma unroll
            for (int reg = 0; reg < 4; ++reg) {
                int row = mt*16 + q4*4 + reg;
                s_n1bf[row*72 + col] = f2bf(silu_f(acc[reg] + nbc));
            }
        }
        __syncthreads();    // B4

        // ---- node GEMM2: h += n1@Wn2 + b2 ----
        {
            int mt = wave & 1, nt = wave >> 1;
            s8v b0 = *(const s8v*)(wl + 24576 + ((nt*2+0)*64 + lane)*8);
            s8v b1 = *(const s8v*)(wl + 24576 + ((nt*2+1)*64 + lane)*8);
            int col = nt*16 + c16;
            float nb2_v = node_b2[l*64 + col];
            s8v a0 = *(const s8v*)(s_n1bf + (mt*16 + c16)*72 +      q4*8);
            s8v a1 = *(const s8v*)(s_n1bf + (mt*16 + c16)*72 + 32 + q4*8);
            v4f acc = {0.f,0.f,0.f,0.f};
            acc = __builtin_amdgcn_mfma_f32_16x16x32_bf16(a0, b0, acc, 0,0,0);
            acc = __builtin_amdgcn_mfma_f32_16x16x32_bf16(a1, b1, acc, 0,0,0);
#pragma unroll
            for (int reg = 0; reg < 4; ++reg) {
                int row = mt*16 + q4*4 + reg;
                float hn = s_h[row*65 + col] + acc[reg] + nb2_v;
                s_h[row*65 + col] = hn;
                s_habf[row*136 + col] = f2bf(hn);
            }
        }
        __syncthreads();    // B5
    }

    // ---------------- epilogue ----------------
    if (tid == 0) {
        float a=s_lat[0],b=s_lat[1],cc=s_lat[2];
        float d=s_lat[3],e=s_lat[4],f =s_lat[5];
        float g=s_lat[6],h2=s_lat[7],i2=s_lat[8];
        float A  =  (e*i2 - f*h2);
        float Bm = -(d*i2 - f*g);
        float C  =  (d*h2 - e*g);
        float det = a*A + b*Bm + cc*C;
        float rd = 1.0f/det;
        s_inv[0] = A*rd;
        s_inv[1] = -(b*i2 - cc*h2)*rd;
        s_inv[2] =  (b*f  - cc*e )*rd;
        s_inv[3] = Bm*rd;
        s_inv[4] =  (a*i2 - cc*g )*rd;
        s_inv[5] = -(a*f  - cc*d )*rd;
        s_inv[6] = C*rd;
        s_inv[7] = -(a*h2 - b*g  )*rd;
        s_inv[8] =  (a*e  - b*d  )*rd;
    }
    __syncthreads();
    if (tid < 96) {
        int r = tid/3, j = tid%3;
        float v = s_shift[r*3+0]*s_inv[0*3+j]
                + s_shift[r*3+1]*s_inv[1*3+j]
                + s_shift[r*3+2]*s_inv[2*3+j];
        out[(base + r)*3 + j] = v;
    }
    for (int q = tid; q < 2048; q += 512) {
        int row = q >> 6, colq = q & 63;
        out[NN*3 + base*64 + q] = s_h[row*65 + colq];
    }
}

extern "C" void kernel_launch(void* const* d_in, const int* in_sizes, int n_in,
                              void* d_out, int out_size, void* d_ws, size_t ws_size,
                              hipStream_t stream) {
    unsigned short* wbf = (unsigned short*)d_ws;
    prepack_w<<<(4*WPL/8 + 255)/256, 256, 0, stream>>>(
        (const float*)d_in[12], (const float*)d_in[14], (const float*)d_in[16],
        (const float*)d_in[19], (const float*)d_in[21], wbf);
    crystal_fused<<<NB, 512, 0, stream>>>(
        (const float*)d_in[0],  (const float*)d_in[1],  (const float*)d_in[2],  (const float*)d_in[3],
        (const float*)d_in[6],  (const float*)d_in[7],  (const float*)d_in[8],  (const float*)d_in[9],
        (const float*)d_in[10], (const float*)d_in[11],
        (const float*)d_in[12], (const float*)d_in[13], (const float*)d_in[15],
        (const float*)d_in[17], (const float*)d_in[18],
        (const float*)d_in[19], (const float*)d_in[20], (const float*)d_in[22],
        wbf, (float*)d_out);
}

// Round 11
// 211.470 us; speedup vs baseline: 1.0792x; 1.0730x over previous
//
#include <hip/hip_runtime.h>
#include <hip/hip_bf16.h>
#include <math.h>

#define NB 512
#define NPC 32
#define KNN 12
#define NL 4
#define NN (NB*NPC)
#define WPL 28672   // prepacked bf16 weight elems per layer

typedef float v4f __attribute__((ext_vector_type(4)));
typedef short s8v __attribute__((ext_vector_type(8)));   // 16 B = 4 VGPRs

// fast silu: ~5 VALU ops (2 transcendental) vs ~10-op exact divide
__device__ __forceinline__ float silu_f(float x) {
    return x * __builtin_amdgcn_rcpf(1.0f + __builtin_amdgcn_exp2f(x * -1.44269504088896341f));
}

__device__ __forceinline__ unsigned short f2bf(float x) {
    unsigned u = __float_as_uint(x);
    u += 0x7fffu + ((u >> 16) & 1u);
    return (unsigned short)(u >> 16);
}

// packed 2xfloat -> 2xbf16 (v_cvt_pk_bf16_f32 on gfx950)
__device__ __forceinline__ unsigned pk2bf(float a, float b) {
    __hip_bfloat162 t = __float22bfloat162_rn(make_float2(a, b));
    union { __hip_bfloat162 h; unsigned u; } c; c.h = t;
    return c.u;
}

// e/12 for e<384 via magic mul (exact over [0,384))
__device__ __forceinline__ int div12(int e) { return (e * 1366) >> 14; }

// fp32 fallback GEMM (embedding only)
template<int R>
__device__ __forceinline__ void gemm_acc(const float* A, int astride,
                                         const float* __restrict__ Wg,
                                         int K, int lane, float* acc) {
#pragma unroll 2
    for (int kq = 0; kq < (K >> 2); ++kq) {
        float w0 = Wg[(4*kq+0)*64 + lane];
        float w1 = Wg[(4*kq+1)*64 + lane];
        float w2 = Wg[(4*kq+2)*64 + lane];
        float w3 = Wg[(4*kq+3)*64 + lane];
#pragma unroll
        for (int r = 0; r < R; ++r) {
            float4 a = *(const float4*)(A + r*astride + 4*kq);
            acc[r] = fmaf(a.x, w0, acc[r]);
            acc[r] = fmaf(a.y, w1, acc[r]);
            acc[r] = fmaf(a.z, w2, acc[r]);
            acc[r] = fmaf(a.w, w3, acc[r]);
        }
    }
}

// ---------------- prepack (unchanged) ----------------
extern "C" __global__ void prepack_w(const float* __restrict__ edge_w1, const float* __restrict__ edge_w2,
                                     const float* __restrict__ coord_w1, const float* __restrict__ node_w1,
                                     const float* __restrict__ node_w2, unsigned short* __restrict__ wout) {
    int g = blockIdx.x * 256 + threadIdx.x;
    if (g >= 4 * WPL / 8) return;
    int l = (g * 8) / WPL;
    int r = (g * 8) % WPL;
    int base, nKt, mat;
    if      (r < 8192)  { base = 0;     nKt = 2; mat = 0; }
    else if (r < 12288) { base = 8192;  nKt = 2; mat = 1; }
    else if (r < 16384) { base = 12288; nKt = 2; mat = 2; }
    else if (r < 24576) { base = 16384; nKt = 4; mat = 3; }
    else                { base = 24576; nKt = 2; mat = 4; }
    int idx = r - base;
    int lane = (idx >> 3) & 63, t = idx >> 9;
    int kt = t % nKt, nt = t / nKt;
    int k0 = kt*32 + ((lane >> 4) & 3)*8;
    int n  = nt*16 + (lane & 15);
    unsigned short o[8];
#pragma unroll
    for (int j = 0; j < 8; ++j) {
        int k = k0 + j;
        float v;
        if      (mat == 0) v = (n < 64) ? edge_w1[l*193*64 + k*64 + n] : edge_w1[l*193*64 + (64+k)*64 + (n-64)];
        else if (mat == 1) v = edge_w2 [l*4096 + k*64 + n];
        else if (mat == 2) v = coord_w1[l*4096 + k*64 + n];
        else if (mat == 3) v = node_w1 [l*192*64 + k*64 + n];
        else               v = node_w2 [l*4096 + k*64 + n];
        o[j] = f2bf(v);
    }
    *(s8v*)(wout + g*8) = *(s8v*)o;
}

// ---------------- main fused kernel: one block (8 waves) per crystal ----------------
// R11: revert to R8 structure ((512,2), 1 block/CU, zero spill — R9/R10 proved
// >2 waves/SIMD unreachable without spill for this reg footprint). Buy latency
// hiding with ILP instead: software-pipelined m-loop (next tile's emeta/H/G
// LDS reads issued under current tile's MFMA+VALU), and GEMM1/GEMM2 B-frag
// global loads prefetched BEFORE the B3/B4 barriers.
extern "C" __global__ __launch_bounds__(512, 2)
void crystal_fused(const float* __restrict__ z_nodes, const float* __restrict__ t_in,
                   const float* __restrict__ frac,    const float* __restrict__ lattice,
                   const float* __restrict__ time_w1, const float* __restrict__ time_b1,
                   const float* __restrict__ time_w2, const float* __restrict__ time_b2,
                   const float* __restrict__ emb_w,   const float* __restrict__ emb_b,
                   const float* __restrict__ edge_w1, const float* __restrict__ edge_b1,
                   const float* __restrict__ edge_b2, const float* __restrict__ coord_b1,
                   const float* __restrict__ coord_w2,
                   const float* __restrict__ node_w1, const float* __restrict__ node_b1,
                   const float* __restrict__ node_b2,
                   const unsigned short* __restrict__ wbf,
                   float* __restrict__ out)
{
    __shared__ __align__(16) float s_h[32*65];
    __shared__ __align__(16) unsigned short s_habf[32*136];        // bf16 [h | m_i]
    __shared__ __align__(16) unsigned short s_n1bf[32*72];
    __shared__ __align__(16) float s_hs[32*68];                    // stride 68: rows 16B-aligned
    __shared__ __align__(16) float s_hd[32*68];
    __shared__ __align__(16) unsigned short s_tiles16[8*1152];     // per-wave m2 tile; overlaid dcf/zbuf
    __shared__ float s_dsq[32][33];
    __shared__ float2 s_emeta[384];                                // {dist_sq, src bits}
    __shared__ float s_endc[384*3];
    __shared__ float s_frac[32][3];
    __shared__ float s_lat[9], s_inv[9];
    __shared__ float s_sinu[64], s_t1[128], s_tf[64];
    __shared__ float s_tb4[NL*64], s_nb4[NL*64];                   // per-layer t-terms (prologue)
    __shared__ float s_shift[32*3];

    const int tid  = threadIdx.x;
    const int c    = blockIdx.x;
    const int lane = tid & 63;
    const int wave = tid >> 6;       // 0..7
    const int q4   = lane >> 4;
    const int c16  = lane & 15;
    const int base = c * NPC;

    // ---------------- phase 0 ----------------
    if (tid < 96) {
        ((float*)s_frac)[tid] = frac[base*3 + tid];
    } else if (tid < 105) {
        s_lat[tid-96] = lattice[c*9 + (tid-96)];
    } else if (tid >= 128 && tid < 160) {
        int i = tid - 128;
        float freq = expf((float)i * (-9.210340371976184f / 31.0f));
        float ang  = t_in[c] * freq;
        s_sinu[i]    = sinf(ang);
        s_sinu[i+32] = cosf(ang);
    }
    __syncthreads();

    // ---------------- phase 1: PBC pair distances ----------------
    float* dcf = (float*)s_tiles16;      // [1024][3]
    {
        float l00=s_lat[0],l01=s_lat[1],l02=s_lat[2];
        float l10=s_lat[3],l11=s_lat[4],l12=s_lat[5];
        float l20=s_lat[6],l21=s_lat[7],l22=s_lat[8];
        for (int p = tid; p < 1024; p += 512) {
            int i = p >> 5, j = p & 31;
            float dx = s_frac[i][0]-s_frac[j][0];
            float dy = s_frac[i][1]-s_frac[j][1];
            float dz = s_frac[i][2]-s_frac[j][2];
            dx -= rintf(dx); dy -= rintf(dy); dz -= rintf(dz);
            float cx = dx*l00 + dy*l10 + dz*l20;
            float cy = dx*l01 + dy*l11 + dz*l21;
            float cz = dx*l02 + dy*l12 + dz*l22;
            float dd = cx*cx + cy*cy + cz*cz;
            s_dsq[i][j] = (i==j) ? 3.0e38f : dd;
            dcf[p*3+0]=cx; dcf[p*3+1]=cy; dcf[p*3+2]=cz;
        }
    }
    __syncthreads();

    // ---------------- phase 2: KNN (wave0 lanes<32) || time-MLP L1 ----------------
    if (tid < 32) {
        int i = tid;
        for (int k = 0; k < KNN; ++k) {
            float best = 3.9e38f; int bj = 0;
            for (int j = 0; j < 32; ++j) {
                float v = s_dsq[i][j];
                if (v < best) { best = v; bj = j; }
            }
            s_dsq[i][bj] = 3.9e38f;
            int e = i*KNN + k;
            s_emeta[e] = make_float2(best, __int_as_float(bj));
            int p = (i<<5) + bj;
            s_endc[e*3+0] = dcf[p*3+0];
            s_endc[e*3+1] = dcf[p*3+1];
            s_endc[e*3+2] = dcf[p*3+2];
        }
    } else if (tid >= 128 && tid < 256) {
        int jj = tid - 128;
        float p0 = time_b1[jj], p1=0.f, p2=0.f, p3=0.f;
        for (int k = 0; k < 64; k += 4) {
            p0 = fmaf(s_sinu[k+0], time_w1[(k+0)*128+jj], p0);
            p1 = fmaf(s_sinu[k+1], time_w1[(k+1)*128+jj], p1);
            p2 = fmaf(s_sinu[k+2], time_w1[(k+2)*128+jj], p2);
            p3 = fmaf(s_sinu[k+3], time_w1[(k+3)*128+jj], p3);
        }
        s_t1[jj] = silu_f((p0+p1) + (p2+p3));
    }
    __syncthreads();

    // ---------------- phase 3: t_feat ; zero shift ----------------
    if (tid < 64) {
        float p0=time_b2[tid],p1=0.f,p2=0.f,p3=0.f;
        for (int k = 0; k < 128; k += 4) {
            p0 = fmaf(s_t1[k+0], time_w2[(k+0)*64+tid], p0);
            p1 = fmaf(s_t1[k+1], time_w2[(k+1)*64+tid], p1);
            p2 = fmaf(s_t1[k+2], time_w2[(k+2)*64+tid], p2);
            p3 = fmaf(s_t1[k+3], time_w2[(k+3)*64+tid], p3);
        }
        s_tf[tid] = (p0+p1) + (p2+p3);
    } else if (tid < 160) {
        s_shift[tid-64] = 0.0f;
    }
    __syncthreads();

    // ---------------- phase 4: z staging + ALL-layer tb/nb GEMVs ----------------
    float* zbuf = (float*)s_tiles16;     // [32][128]
    for (int q = tid; q < 4096; q += 512) zbuf[q] = z_nodes[base*128 + q];
    {
        int l = wave >> 1, kind = wave & 1;
        const float* Wt = kind ? (node_w1 + l*192*64 + 128*64) : (edge_w1 + l*193*64 + 129*64);
        const float* bb = kind ? (node_b1 + l*64) : (edge_b1 + l*64);
        float p0 = bb[lane], p1=0.f, p2=0.f, p3=0.f;
        for (int k = 0; k < 64; k += 4) {
            p0 = fmaf(s_tf[k+0], Wt[(k+0)*64 + lane], p0);
            p1 = fmaf(s_tf[k+1], Wt[(k+1)*64 + lane], p1);
            p2 = fmaf(s_tf[k+2], Wt[(k+2)*64 + lane], p2);
            p3 = fmaf(s_tf[k+3], Wt[(k+3)*64 + lane], p3);
        }
        float v = (p0+p1) + (p2+p3);
        if (kind) s_nb4[l*64 + lane] = v;
        else      s_tb4[l*64 + lane] = v;
    }
    __syncthreads();

    // ---------------- phase 5: node embedding ----------------
    {
        float acc[4];
#pragma unroll
        for (int r = 0; r < 4; ++r) acc[r] = emb_b[lane];
        gemm_acc<4>(zbuf + (wave*4)*128, 128, emb_w, 128, lane, acc);
#pragma unroll
        for (int r = 0; r < 4; ++r) {
            int row = wave*4 + r;
            s_h[row*65 + lane] = acc[r];
            s_habf[row*136 + lane] = f2bf(acc[r]);
        }
    }
    __syncthreads();    // habf ready for layer 0 step A

    // ---------------- EGNN layers ----------------
    for (int l = 0; l < NL; ++l) {
        const unsigned short* wl = wbf + l*WPL;
        const float* w1row = edge_w1 + l*193*64 + 128*64;   // dist^2 weight row
        float b2e_v[4], cb1_v[4], w2c_v[4];
#pragma unroll
        for (int nt = 0; nt < 4; ++nt) {
            b2e_v[nt] = edge_b2 [l*64 + nt*16 + c16];
            cb1_v[nt] = coord_b1[l*64 + nt*16 + c16];
            w2c_v[nt] = coord_w2[l*64 + nt*16 + c16];
        }

        // ---- step A: [hs|hd] = h @ [W1a|W1b] (+tb on hd) — pure MFMA+store ----
        {
            s8v a[2][2];
#pragma unroll
            for (int mt = 0; mt < 2; ++mt)
#pragma unroll
                for (int kt = 0; kt < 2; ++kt)
                    a[mt][kt] = *(const s8v*)(s_habf + (mt*16 + c16)*136 + kt*32 + q4*8);
            v4f acc[2] = {{0.f,0.f,0.f,0.f},{0.f,0.f,0.f,0.f}};
#pragma unroll
            for (int kt = 0; kt < 2; ++kt) {
                s8v b = *(const s8v*)(wl + ((wave*2+kt)*64 + lane)*8);
#pragma unroll
                for (int mt = 0; mt < 2; ++mt)
                    acc[mt] = __builtin_amdgcn_mfma_f32_16x16x32_bf16(a[mt][kt], b, acc[mt], 0, 0, 0);
            }
            int col = wave*16 + c16;
            if (wave < 4) {
#pragma unroll
                for (int mt = 0; mt < 2; ++mt)
#pragma unroll
                    for (int reg = 0; reg < 4; ++reg)
                        s_hs[(mt*16 + q4*4 + reg)*68 + col] = acc[mt][reg];
            } else {
                int colb = col - 64;
                float tbv = s_tb4[l*64 + colb];
#pragma unroll
                for (int mt = 0; mt < 2; ++mt)
#pragma unroll
                    for (int reg = 0; reg < 4; ++reg)
                        s_hd[(mt*16 + q4*4 + reg)*68 + colb] = acc[mt][reg] + tbv;
            }
        }
        __syncthreads();    // B2

        // ---- edge phase: wave owns 48 edges (dsts wave*4..+3), 3 tiles of 16 ----
        // Software-pipelined: tile m+1's emeta/H/G LDS reads issue under tile m's
        // MFMA/VALU; lgkmcnt(0) drain is harmless (in-order LDS, prefetch done first).
        {
            s8v w2f[8], wc1f[8];
#pragma unroll
            for (int nt = 0; nt < 4; ++nt)
#pragma unroll
                for (int kt = 0; kt < 2; ++kt) {
                    w2f [nt*2+kt] = *(const s8v*)(wl +  8192 + ((nt*2+kt)*64 + lane)*8);
                    wc1f[nt*2+kt] = *(const s8v*)(wl + 12288 + ((nt*2+kt)*64 + lane)*8);
                }
            union F4 { float4 v; float f[4]; };
            F4 W4[4];
            W4[0].v = *(const float4*)(w1row + q4*8);
            W4[1].v = *(const float4*)(w1row + q4*8 + 4);
            W4[2].v = *(const float4*)(w1row + 32 + q4*8);
            W4[3].v = *(const float4*)(w1row + 32 + q4*8 + 4);

            unsigned short* tile = s_tiles16 + wave*1152;
            float miacc[4][4];
#pragma unroll
            for (int a2 = 0; a2 < 4; ++a2)
#pragma unroll
                for (int b2 = 0; b2 < 4; ++b2) miacc[a2][b2] = 0.f;

            // all 3 tiles' edge meta upfront (independent ds_reads, overlap)
            float2 me0 = s_emeta[wave*48 +  0 + c16];
            float2 me1 = s_emeta[wave*48 + 16 + c16];
            float2 me2 = s_emeta[wave*48 + 32 + c16];

            // preload tile 0 rows
            F4 H[4], G[4];
            {
                int srcn = __float_as_int(me0.y);
                int dstn = div12(wave*48 + c16);
                const float* hsr = s_hs + srcn*68 + q4*8;
                const float* hdr = s_hd + dstn*68 + q4*8;
                H[0].v = *(const float4*)(hsr);      H[1].v = *(const float4*)(hsr+4);
                H[2].v = *(const float4*)(hsr+32);   H[3].v = *(const float4*)(hsr+36);
                G[0].v = *(const float4*)(hdr);      G[1].v = *(const float4*)(hdr+4);
                G[2].v = *(const float4*)(hdr+32);   G[3].v = *(const float4*)(hdr+36);
            }

#pragma unroll
            for (int m = 0; m < 3; ++m) {
                const int e0g = wave*48 + m*16;
                const float dq = (m==0) ? me0.x : (m==1) ? me1.x : me2.x;
                // build A-frags from preloaded H/G
                union S8 { s8v v; unsigned u[4]; } A0, A1;
#pragma unroll
                for (int g2 = 0; g2 < 4; ++g2) {
                    float s0 = silu_f(fmaf(dq, W4[g2].f[0], H[g2].f[0] + G[g2].f[0]));
                    float s1 = silu_f(fmaf(dq, W4[g2].f[1], H[g2].f[1] + G[g2].f[1]));
                    float s2 = silu_f(fmaf(dq, W4[g2].f[2], H[g2].f[2] + G[g2].f[2]));
                    float s3 = silu_f(fmaf(dq, W4[g2].f[3], H[g2].f[3] + G[g2].f[3]));
                    unsigned lo = pk2bf(s0, s1), hi2 = pk2bf(s2, s3);
                    if (g2 < 2) { A0.u[g2*2] = lo; A0.u[g2*2+1] = hi2; }
                    else        { A1.u[(g2-2)*2] = lo; A1.u[(g2-2)*2+1] = hi2; }
                }
                // prefetch tile m+1 rows (H/G dead now; loads hide under m2/cw below)
                if (m < 2) {
                    float2 men = (m==0) ? me1 : me2;
                    int srcn = __float_as_int(men.y);
                    int dstn = div12(e0g + 16 + c16);
                    const float* hsr = s_hs + srcn*68 + q4*8;
                    const float* hdr = s_hd + dstn*68 + q4*8;
                    H[0].v = *(const float4*)(hsr);      H[1].v = *(const float4*)(hsr+4);
                    H[2].v = *(const float4*)(hsr+32);   H[3].v = *(const float4*)(hsr+36);
                    G[0].v = *(const float4*)(hdr);      G[1].v = *(const float4*)(hdr+4);
                    G[2].v = *(const float4*)(hdr+32);   G[3].v = *(const float4*)(hdr+36);
                }

                // m2 = silu(m1@W2 + b2): cached w2f; mi in regs
                const int thr = (m==0) ? 3 : (m==1) ? 2 : 1;   // q4>=thr -> second dst
                const int dlo = m;                              // local dst ids {m, m+1}
#pragma unroll
                for (int nt = 0; nt < 4; ++nt) {
                    v4f acc = {0.f,0.f,0.f,0.f};
                    acc = __builtin_amdgcn_mfma_f32_16x16x32_bf16(A0.v, w2f[nt*2+0], acc, 0,0,0);
                    acc = __builtin_amdgcn_mfma_f32_16x16x32_bf16(A1.v, w2f[nt*2+1], acc, 0,0,0);
                    int col = nt*16 + c16;
                    float msum = 0.f;
#pragma unroll
                    for (int reg = 0; reg < 4; ++reg) {
                        float v = silu_f(acc[reg] + b2e_v[nt]);
                        tile[(q4*4 + reg)*72 + col] = f2bf(v);
                        msum += v;
                    }
                    bool hi = (q4 >= thr);
                    miacc[nt][dlo]   += hi ? 0.f : msum;
                    miacc[nt][dlo+1] += hi ? msum : 0.f;
                }
                asm volatile("s_waitcnt lgkmcnt(0)" ::: "memory");
                s8v c0 = *(const s8v*)(tile + c16*72 +      q4*8);
                s8v c1 = *(const s8v*)(tile + c16*72 + 32 + q4*8);
                // cw = silu(m2@Wc1 + cb1) . w2c
                float cwp[4] = {0.f,0.f,0.f,0.f};
#pragma unroll
                for (int nt = 0; nt < 4; ++nt) {
                    v4f acc = {0.f,0.f,0.f,0.f};
                    acc = __builtin_amdgcn_mfma_f32_16x16x32_bf16(c0, wc1f[nt*2+0], acc, 0,0,0);
                    acc = __builtin_amdgcn_mfma_f32_16x16x32_bf16(c1, wc1f[nt*2+1], acc, 0,0,0);
#pragma unroll
                    for (int reg = 0; reg < 4; ++reg)
                        cwp[reg] += silu_f(acc[reg] + cb1_v[nt]) * w2c_v[nt];
                }
#pragma unroll
                for (int reg = 0; reg < 4; ++reg) {
                    float v = cwp[reg];
                    v += __shfl_xor(v, 1); v += __shfl_xor(v, 2);
                    v += __shfl_xor(v, 4); v += __shfl_xor(v, 8);
                    int e = e0g + q4*4 + reg;
                    if (c16 < 3) {
                        int src = __float_as_int(s_emeta[e].y);
                        atomicAdd(&s_shift[src*3 + c16], s_endc[e*3 + c16] * v);
                    }
                }
            }
            // mi: reduce across q4 groups, write bf16 into habf cols 64..127
#pragma unroll
            for (int nt = 0; nt < 4; ++nt)
#pragma unroll
                for (int d = 0; d < 4; ++d) {
                    float v = miacc[nt][d];
                    v += __shfl_xor(v, 16);
                    v += __shfl_xor(v, 32);
                    s_habf[(wave*4 + d)*136 + 64 + nt*16 + c16] = f2bf(v);
                }
        }

        // prefetch GEMM1 B-frags BEFORE the barrier (global loads, barrier-independent)
        const int ntA = wave >> 1, mtA = wave & 1;
        s8v bn1[4];
#pragma unroll
        for (int kt = 0; kt < 4; ++kt)
            bn1[kt] = *(const s8v*)(wl + 16384 + ((ntA*4+kt)*64 + lane)*8);
        __syncthreads();    // B3

        // ---- node GEMM1: wave -> (mt, nt) sub-tile ----
        {
            int col = ntA*16 + c16;
            float nbc = s_nb4[l*64 + col];
            v4f acc = {0.f,0.f,0.f,0.f};
#pragma unroll
            for (int kt = 0; kt < 4; ++kt) {
                s8v a = *(const s8v*)(s_habf + (mtA*16 + c16)*136 + kt*32 + q4*8);
                acc = __builtin_amdgcn_mfma_f32_16x16x32_bf16(a, bn1[kt], acc, 0,0,0);
            }
#pragma unroll
            for (int reg = 0; reg < 4; ++reg) {
                int row = mtA*16 + q4*4 + reg;
                s_n1bf[row*72 + col] = f2bf(silu_f(acc[reg] + nbc));
            }
        }
        // prefetch GEMM2 B-frags before B4
        s8v bn20 = *(const s8v*)(wl + 24576 + ((ntA*2+0)*64 + lane)*8);
        s8v bn21 = *(const s8v*)(wl + 24576 + ((ntA*2+1)*64 + lane)*8);
        __syncthreads();    // B4

        // ---- node GEMM2: h += n1@Wn2 + b2 ----
        {
            int col = ntA*16 + c16;
            float nb2_v = node_b2[l*64 + col];
            s8v a0 = *(const s8v*)(s_n1bf + (mtA*16 + c16)*72 +      q4*8);
            s8v a1 = *(const s8v*)(s_n1bf + (mtA*16 + c16)*72 + 32 + q4*8);
            v4f acc = {0.f,0.f,0.f,0.f};
            acc = __builtin_amdgcn_mfma_f32_16x16x32_bf16(a0, bn20, acc, 0,0,0);
            acc = __builtin_amdgcn_mfma_f32_16x16x32_bf16(a1, bn21, acc, 0,0,0);
#pragma unroll
            for (int reg = 0; reg < 4; ++reg) {
                int row = mtA*16 + q4*4 + reg;
                float hn = s_h[row*65 + col] + acc[reg] + nb2_v;
                s_h[row*65 + col] = hn;
                s_habf[row*136 + col] = f2bf(hn);
            }
        }
        __syncthreads();    // B5
    }

    // ---------------- epilogue ----------------
    if (tid == 0) {
        float a=s_lat[0],b=s_lat[1],cc=s_lat[2];
        float d=s_lat[3],e=s_lat[4],f =s_lat[5];
        float g=s_lat[6],h2=s_lat[7],i2=s_lat[8];
        float A  =  (e*i2 - f*h2);
        float Bm = -(d*i2 - f*g);
        float C  =  (d*h2 - e*g);
        float det = a*A + b*Bm + cc*C;
        float rd = 1.0f/det;
        s_inv[0] = A*rd;
        s_inv[1] = -(b*i2 - cc*h2)*rd;
        s_inv[2] =  (b*f  - cc*e )*rd;
        s_inv[3] = Bm*rd;
        s_inv[4] =  (a*i2 - cc*g )*rd;
        s_inv[5] = -(a*f  - cc*d )*rd;
        s_inv[6] = C*rd;
        s_inv[7] = -(a*h2 - b*g  )*rd;
        s_inv[8] =  (a*e  - b*d  )*rd;
    }
    __syncthreads();
    if (tid < 96) {
        int r = tid/3, j = tid%3;
        float v = s_shift[r*3+0]*s_inv[0*3+j]
                + s_shift[r*3+1]*s_inv[1*3+j]
                + s_shift[r*3+2]*s_inv[2*3+j];
        out[(base + r)*3 + j] = v;
    }
    for (int q = tid; q < 2048; q += 512) {
        int row = q >> 6, colq = q & 63;
        out[NN*3 + base*64 + q] = s_h[row*65 + colq];
    }
}

extern "C" void kernel_launch(void* const* d_in, const int* in_sizes, int n_in,
                              void* d_out, int out_size, void* d_ws, size_t ws_size,
                              hipStream_t stream) {
    unsigned short* wbf = (unsigned short*)d_ws;
    prepack_w<<<(4*WPL/8 + 255)/256, 256, 0, stream>>>(
        (const float*)d_in[12], (const float*)d_in[14], (const float*)d_in[16],
        (const float*)d_in[19], (const float*)d_in[21], wbf);
    crystal_fused<<<NB, 512, 0, stream>>>(
        (const float*)d_in[0],  (const float*)d_in[1],  (const float*)d_in[2],  (const float*)d_in[3],
        (const float*)d_in[6],  (const float*)d_in[7],  (const float*)d_in[8],  (const float*)d_in[9],
        (const float*)d_in[10], (const float*)d_in[11],
        (const float*)d_in[12], (const float*)d_in[13], (const float*)d_in[15],
        (const float*)d_in[17], (const float*)d_in[18],
        (const float*)d_in[19], (const float*)d_in[20], (const float*)d_in[22],
        wbf, (float*)d_out);
}

// Round 12
// 200.676 us; speedup vs baseline: 1.1372x; 1.0538x over previous
//
#include <hip/hip_runtime.h>
#include <hip/hip_bf16.h>
#include <math.h>

#define NB 512
#define NPC 32
#define KNN 12
#define NL 4
#define NN (NB*NPC)
#define WPL 28672   // prepacked bf16 weight elems per layer

typedef float v4f __attribute__((ext_vector_type(4)));
typedef short s8v __attribute__((ext_vector_type(8)));   // 16 B = 4 VGPRs

// fast silu: ~5 VALU ops (2 transcendental) vs ~10-op exact divide
__device__ __forceinline__ float silu_f(float x) {
    return x * __builtin_amdgcn_rcpf(1.0f + __builtin_amdgcn_exp2f(x * -1.44269504088896341f));
}

__device__ __forceinline__ unsigned short f2bf(float x) {
    unsigned u = __float_as_uint(x);
    u += 0x7fffu + ((u >> 16) & 1u);
    return (unsigned short)(u >> 16);
}

// packed 2xfloat -> 2xbf16 (v_cvt_pk_bf16_f32 on gfx950)
__device__ __forceinline__ unsigned pk2bf(float a, float b) {
    __hip_bfloat162 t = __float22bfloat162_rn(make_float2(a, b));
    union { __hip_bfloat162 h; unsigned u; } c; c.h = t;
    return c.u;
}

// e/12 for e<384 via magic mul (exact over [0,384))
__device__ __forceinline__ int div12(int e) { return (e * 1366) >> 14; }

// fp32 fallback GEMM (embedding only)
template<int R>
__device__ __forceinline__ void gemm_acc(const float* A, int astride,
                                         const float* __restrict__ Wg,
                                         int K, int lane, float* acc) {
#pragma unroll 2
    for (int kq = 0; kq < (K >> 2); ++kq) {
        float w0 = Wg[(4*kq+0)*64 + lane];
        float w1 = Wg[(4*kq+1)*64 + lane];
        float w2 = Wg[(4*kq+2)*64 + lane];
        float w3 = Wg[(4*kq+3)*64 + lane];
#pragma unroll
        for (int r = 0; r < R; ++r) {
            float4 a = *(const float4*)(A + r*astride + 4*kq);
            acc[r] = fmaf(a.x, w0, acc[r]);
            acc[r] = fmaf(a.y, w1, acc[r]);
            acc[r] = fmaf(a.z, w2, acc[r]);
            acc[r] = fmaf(a.w, w3, acc[r]);
        }
    }
}

// ---------------- prepack (unchanged) ----------------
extern "C" __global__ void prepack_w(const float* __restrict__ edge_w1, const float* __restrict__ edge_w2,
                                     const float* __restrict__ coord_w1, const float* __restrict__ node_w1,
                                     const float* __restrict__ node_w2, unsigned short* __restrict__ wout) {
    int g = blockIdx.x * 256 + threadIdx.x;
    if (g >= 4 * WPL / 8) return;
    int l = (g * 8) / WPL;
    int r = (g * 8) % WPL;
    int base, nKt, mat;
    if      (r < 8192)  { base = 0;     nKt = 2; mat = 0; }
    else if (r < 12288) { base = 8192;  nKt = 2; mat = 1; }
    else if (r < 16384) { base = 12288; nKt = 2; mat = 2; }
    else if (r < 24576) { base = 16384; nKt = 4; mat = 3; }
    else                { base = 24576; nKt = 2; mat = 4; }
    int idx = r - base;
    int lane = (idx >> 3) & 63, t = idx >> 9;
    int kt = t % nKt, nt = t / nKt;
    int k0 = kt*32 + ((lane >> 4) & 3)*8;
    int n  = nt*16 + (lane & 15);
    unsigned short o[8];
#pragma unroll
    for (int j = 0; j < 8; ++j) {
        int k = k0 + j;
        float v;
        if      (mat == 0) v = (n < 64) ? edge_w1[l*193*64 + k*64 + n] : edge_w1[l*193*64 + (64+k)*64 + (n-64)];
        else if (mat == 1) v = edge_w2 [l*4096 + k*64 + n];
        else if (mat == 2) v = coord_w1[l*4096 + k*64 + n];
        else if (mat == 3) v = node_w1 [l*192*64 + k*64 + n];
        else               v = node_w2 [l*4096 + k*64 + n];
        o[j] = f2bf(v);
    }
    *(s8v*)(wout + g*8) = *(s8v*)o;
}

// ---------------- main fused kernel: one block (4 waves) per crystal ----------------
// R12: 256-thread blocks -> 2 independent blocks/CU (same 8 waves/CU, same regs,
// zero spill). Barrier stalls decorrelate: when block A drains at a barrier,
// block B's waves issue. All 512 blocks co-resident (no 2-round serialization).
// Per-wave work doubles (2 step-A ntiles, 6 edge tiles, 2 node sub-tiles);
// m_i uses a rolling 2-slot register window with per-tile flushes.
extern "C" __global__ __launch_bounds__(256, 2)
void crystal_fused(const float* __restrict__ z_nodes, const float* __restrict__ t_in,
                   const float* __restrict__ frac,    const float* __restrict__ lattice,
                   const float* __restrict__ time_w1, const float* __restrict__ time_b1,
                   const float* __restrict__ time_w2, const float* __restrict__ time_b2,
                   const float* __restrict__ emb_w,   const float* __restrict__ emb_b,
                   const float* __restrict__ edge_w1, const float* __restrict__ edge_b1,
                   const float* __restrict__ edge_b2, const float* __restrict__ coord_b1,
                   const float* __restrict__ coord_w2,
                   const float* __restrict__ node_w1, const float* __restrict__ node_b1,
                   const float* __restrict__ node_b2,
                   const unsigned short* __restrict__ wbf,
                   float* __restrict__ out)
{
    __shared__ __align__(16) float s_h[32*65];
    __shared__ __align__(16) unsigned short s_habf[32*136];        // bf16 [h | m_i]
    __shared__ __align__(16) unsigned short s_n1bf[32*72];
    __shared__ __align__(16) float s_hs[32*68];                    // stride 68: rows 16B-aligned
    __shared__ __align__(16) float s_hd[32*68];
    __shared__ __align__(16) unsigned short s_tiles16[8192];       // 16KB: per-wave m2 tiles (4x1152) / dcf / zbuf
    __shared__ float s_dsq[32][33];
    __shared__ float2 s_emeta[384];                                // {dist_sq, src bits}
    __shared__ float s_endc[384*3];
    __shared__ float s_frac[32][3];
    __shared__ float s_lat[9], s_inv[9];
    __shared__ float s_sinu[64], s_t1[128], s_tf[64];
    __shared__ float s_tb4[NL*64], s_nb4[NL*64];                   // per-layer t-terms (prologue)
    __shared__ float s_shift[32*3];

    const int tid  = threadIdx.x;
    const int c    = blockIdx.x;
    const int lane = tid & 63;
    const int wave = tid >> 6;       // 0..3
    const int q4   = lane >> 4;
    const int c16  = lane & 15;
    const int base = c * NPC;

    // ---------------- phase 0 ----------------
    if (tid < 96) {
        ((float*)s_frac)[tid] = frac[base*3 + tid];
    } else if (tid < 105) {
        s_lat[tid-96] = lattice[c*9 + (tid-96)];
    } else if (tid >= 128 && tid < 160) {
        int i = tid - 128;
        float freq = expf((float)i * (-9.210340371976184f / 31.0f));
        float ang  = t_in[c] * freq;
        s_sinu[i]    = sinf(ang);
        s_sinu[i+32] = cosf(ang);
    }
    __syncthreads();

    // ---------------- phase 1: PBC pair distances ----------------
    float* dcf = (float*)s_tiles16;      // [1024][3] = 12KB
    {
        float l00=s_lat[0],l01=s_lat[1],l02=s_lat[2];
        float l10=s_lat[3],l11=s_lat[4],l12=s_lat[5];
        float l20=s_lat[6],l21=s_lat[7],l22=s_lat[8];
        for (int p = tid; p < 1024; p += 256) {
            int i = p >> 5, j = p & 31;
            float dx = s_frac[i][0]-s_frac[j][0];
            float dy = s_frac[i][1]-s_frac[j][1];
            float dz = s_frac[i][2]-s_frac[j][2];
            dx -= rintf(dx); dy -= rintf(dy); dz -= rintf(dz);
            float cx = dx*l00 + dy*l10 + dz*l20;
            float cy = dx*l01 + dy*l11 + dz*l21;
            float cz = dx*l02 + dy*l12 + dz*l22;
            float dd = cx*cx + cy*cy + cz*cz;
            s_dsq[i][j] = (i==j) ? 3.0e38f : dd;
            dcf[p*3+0]=cx; dcf[p*3+1]=cy; dcf[p*3+2]=cz;
        }
    }
    __syncthreads();

    // ---------------- phase 2: KNN (wave0 lanes<32) || time-MLP L1 (waves 2,3) ----------------
    if (tid < 32) {
        int i = tid;
        for (int k = 0; k < KNN; ++k) {
            float best = 3.9e38f; int bj = 0;
            for (int j = 0; j < 32; ++j) {
                float v = s_dsq[i][j];
                if (v < best) { best = v; bj = j; }
            }
            s_dsq[i][bj] = 3.9e38f;
            int e = i*KNN + k;
            s_emeta[e] = make_float2(best, __int_as_float(bj));
            int p = (i<<5) + bj;
            s_endc[e*3+0] = dcf[p*3+0];
            s_endc[e*3+1] = dcf[p*3+1];
            s_endc[e*3+2] = dcf[p*3+2];
        }
    } else if (tid >= 128) {
        int jj = tid - 128;
        float p0 = time_b1[jj], p1=0.f, p2=0.f, p3=0.f;
        for (int k = 0; k < 64; k += 4) {
            p0 = fmaf(s_sinu[k+0], time_w1[(k+0)*128+jj], p0);
            p1 = fmaf(s_sinu[k+1], time_w1[(k+1)*128+jj], p1);
            p2 = fmaf(s_sinu[k+2], time_w1[(k+2)*128+jj], p2);
            p3 = fmaf(s_sinu[k+3], time_w1[(k+3)*128+jj], p3);
        }
        s_t1[jj] = silu_f((p0+p1) + (p2+p3));
    }
    __syncthreads();

    // ---------------- phase 3: t_feat ; zero shift ----------------
    if (tid < 64) {
        float p0=time_b2[tid],p1=0.f,p2=0.f,p3=0.f;
        for (int k = 0; k < 128; k += 4) {
            p0 = fmaf(s_t1[k+0], time_w2[(k+0)*64+tid], p0);
            p1 = fmaf(s_t1[k+1], time_w2[(k+1)*64+tid], p1);
            p2 = fmaf(s_t1[k+2], time_w2[(k+2)*64+tid], p2);
            p3 = fmaf(s_t1[k+3], time_w2[(k+3)*64+tid], p3);
        }
        s_tf[tid] = (p0+p1) + (p2+p3);
    } else if (tid < 160) {
        s_shift[tid-64] = 0.0f;
    }
    __syncthreads();

    // ---------------- phase 4: z staging + ALL-layer tb/nb GEMVs (2 tasks/wave) ----------------
    float* zbuf = (float*)s_tiles16;     // [32][128] = 16KB
    for (int q = tid; q < 4096; q += 256) zbuf[q] = z_nodes[base*128 + q];
#pragma unroll
    for (int it = 0; it < 2; ++it) {
        int t = wave + it*4;
        int lt = t >> 1, kind = t & 1;
        const float* Wt = kind ? (node_w1 + lt*192*64 + 128*64) : (edge_w1 + lt*193*64 + 129*64);
        const float* bb = kind ? (node_b1 + lt*64) : (edge_b1 + lt*64);
        float p0 = bb[lane], p1=0.f, p2=0.f, p3=0.f;
        for (int k = 0; k < 64; k += 4) {
            p0 = fmaf(s_tf[k+0], Wt[(k+0)*64 + lane], p0);
            p1 = fmaf(s_tf[k+1], Wt[(k+1)*64 + lane], p1);
            p2 = fmaf(s_tf[k+2], Wt[(k+2)*64 + lane], p2);
            p3 = fmaf(s_tf[k+3], Wt[(k+3)*64 + lane], p3);
        }
        float v = (p0+p1) + (p2+p3);
        if (kind) s_nb4[lt*64 + lane] = v;
        else      s_tb4[lt*64 + lane] = v;
    }
    __syncthreads();

    // ---------------- phase 5: node embedding (8 rows/wave) ----------------
    {
        float acc[8];
#pragma unroll
        for (int r = 0; r < 8; ++r) acc[r] = emb_b[lane];
        gemm_acc<8>(zbuf + (wave*8)*128, 128, emb_w, 128, lane, acc);
#pragma unroll
        for (int r = 0; r < 8; ++r) {
            int row = wave*8 + r;
            s_h[row*65 + lane] = acc[r];
            s_habf[row*136 + lane] = f2bf(acc[r]);
        }
    }
    __syncthreads();    // habf ready for layer 0 step A

    // ---------------- EGNN layers ----------------
    for (int l = 0; l < NL; ++l) {
        const unsigned short* wl = wbf + l*WPL;
        const float* w1row = edge_w1 + l*193*64 + 128*64;   // dist^2 weight row
        float b2e_v[4], cb1_v[4], w2c_v[4];
#pragma unroll
        for (int nt = 0; nt < 4; ++nt) {
            b2e_v[nt] = edge_b2 [l*64 + nt*16 + c16];
            cb1_v[nt] = coord_b1[l*64 + nt*16 + c16];
            w2c_v[nt] = coord_w2[l*64 + nt*16 + c16];
        }

        // ---- step A: wave w -> hs ntile w AND hd ntile w (shared A-frags) ----
        {
            s8v a[2][2];
#pragma unroll
            for (int mt = 0; mt < 2; ++mt)
#pragma unroll
                for (int kt = 0; kt < 2; ++kt)
                    a[mt][kt] = *(const s8v*)(s_habf + (mt*16 + c16)*136 + kt*32 + q4*8);
            v4f accS[2] = {{0.f,0.f,0.f,0.f},{0.f,0.f,0.f,0.f}};
            v4f accD[2] = {{0.f,0.f,0.f,0.f},{0.f,0.f,0.f,0.f}};
#pragma unroll
            for (int kt = 0; kt < 2; ++kt) {
                s8v bS = *(const s8v*)(wl + ((wave*2+kt)*64 + lane)*8);
                s8v bD = *(const s8v*)(wl + (((wave+4)*2+kt)*64 + lane)*8);
#pragma unroll
                for (int mt = 0; mt < 2; ++mt) {
                    accS[mt] = __builtin_amdgcn_mfma_f32_16x16x32_bf16(a[mt][kt], bS, accS[mt], 0, 0, 0);
                    accD[mt] = __builtin_amdgcn_mfma_f32_16x16x32_bf16(a[mt][kt], bD, accD[mt], 0, 0, 0);
                }
            }
            int col = wave*16 + c16;
            float tbv = s_tb4[l*64 + col];
#pragma unroll
            for (int mt = 0; mt < 2; ++mt)
#pragma unroll
                for (int reg = 0; reg < 4; ++reg) {
                    int row = mt*16 + q4*4 + reg;
                    s_hs[row*68 + col] = accS[mt][reg];
                    s_hd[row*68 + col] = accD[mt][reg] + tbv;
                }
        }
        __syncthreads();    // B2

        // ---- edge phase: wave owns 96 edges (dsts wave*8..+7), 6 tiles of 16 ----
        {
            s8v w2f[8], wc1f[8];
#pragma unroll
            for (int nt = 0; nt < 4; ++nt)
#pragma unroll
                for (int kt = 0; kt < 2; ++kt) {
                    w2f [nt*2+kt] = *(const s8v*)(wl +  8192 + ((nt*2+kt)*64 + lane)*8);
                    wc1f[nt*2+kt] = *(const s8v*)(wl + 12288 + ((nt*2+kt)*64 + lane)*8);
                }
            union F4 { float4 v; float f[4]; };
            F4 W4[4];
            W4[0].v = *(const float4*)(w1row + q4*8);
            W4[1].v = *(const float4*)(w1row + q4*8 + 4);
            W4[2].v = *(const float4*)(w1row + 32 + q4*8);
            W4[3].v = *(const float4*)(w1row + 32 + q4*8 + 4);

            unsigned short* tile = s_tiles16 + wave*1152;
            float miacc[4][2];   // rolling 2-slot window (slot = dst&1)
#pragma unroll
            for (int a2 = 0; a2 < 4; ++a2) { miacc[a2][0] = 0.f; miacc[a2][1] = 0.f; }

            auto flushd = [&](int d) {
                int s = d & 1;
#pragma unroll
                for (int nt = 0; nt < 4; ++nt) {
                    float v = miacc[nt][s];
                    v += __shfl_xor(v, 16);
                    v += __shfl_xor(v, 32);
                    s_habf[(wave*8 + d)*136 + 64 + nt*16 + c16] = f2bf(v);
                    miacc[nt][s] = 0.f;
                }
            };

            // all 6 tiles' edge meta upfront
            float2 me0 = s_emeta[wave*96 +  0 + c16];
            float2 me1 = s_emeta[wave*96 + 16 + c16];
            float2 me2 = s_emeta[wave*96 + 32 + c16];
            float2 me3 = s_emeta[wave*96 + 48 + c16];
            float2 me4 = s_emeta[wave*96 + 64 + c16];
            float2 me5 = s_emeta[wave*96 + 80 + c16];

            // preload tile 0 rows
            F4 H[4], G[4];
            {
                int srcn = __float_as_int(me0.y);
                int dstn = div12(wave*96 + c16);
                const float* hsr = s_hs + srcn*68 + q4*8;
                const float* hdr = s_hd + dstn*68 + q4*8;
                H[0].v = *(const float4*)(hsr);      H[1].v = *(const float4*)(hsr+4);
                H[2].v = *(const float4*)(hsr+32);   H[3].v = *(const float4*)(hsr+36);
                G[0].v = *(const float4*)(hdr);      G[1].v = *(const float4*)(hdr+4);
                G[2].v = *(const float4*)(hdr+32);   G[3].v = *(const float4*)(hdr+36);
            }

#pragma unroll
            for (int m = 0; m < 6; ++m) {
                const int e0g = wave*96 + m*16;
                const float dq = (m==0) ? me0.x : (m==1) ? me1.x : (m==2) ? me2.x
                               : (m==3) ? me3.x : (m==4) ? me4.x : me5.x;
                // build A-frags from preloaded H/G
                union S8 { s8v v; unsigned u[4]; } A0, A1;
#pragma unroll
                for (int g2 = 0; g2 < 4; ++g2) {
                    float s0 = silu_f(fmaf(dq, W4[g2].f[0], H[g2].f[0] + G[g2].f[0]));
                    float s1 = silu_f(fmaf(dq, W4[g2].f[1], H[g2].f[1] + G[g2].f[1]));
                    float s2 = silu_f(fmaf(dq, W4[g2].f[2], H[g2].f[2] + G[g2].f[2]));
                    float s3 = silu_f(fmaf(dq, W4[g2].f[3], H[g2].f[3] + G[g2].f[3]));
                    unsigned lo = pk2bf(s0, s1), hi2 = pk2bf(s2, s3);
                    if (g2 < 2) { A0.u[g2*2] = lo; A0.u[g2*2+1] = hi2; }
                    else        { A1.u[(g2-2)*2] = lo; A1.u[(g2-2)*2+1] = hi2; }
                }
                // prefetch tile m+1 rows (hides under m2/cw below)
                if (m < 5) {
                    float2 men = (m==0) ? me1 : (m==1) ? me2 : (m==2) ? me3
                               : (m==3) ? me4 : me5;
                    int srcn = __float_as_int(men.y);
                    int dstn = div12(e0g + 16 + c16);
                    const float* hsr = s_hs + srcn*68 + q4*8;
                    const float* hdr = s_hd + dstn*68 + q4*8;
                    H[0].v = *(const float4*)(hsr);      H[1].v = *(const float4*)(hsr+4);
                    H[2].v = *(const float4*)(hsr+32);   H[3].v = *(const float4*)(hsr+36);
                    G[0].v = *(const float4*)(hdr);      G[1].v = *(const float4*)(hdr+4);
                    G[2].v = *(const float4*)(hdr+32);   G[3].v = *(const float4*)(hdr+36);
                }

                // m2 = silu(m1@W2 + b2): cached w2f; mi into rolling slots
                const int dlo = (m < 3) ? m : m + 1;           // local dst ids {dlo, dlo+1}
                const int thr = 3 - (m % 3);                   // q4>=thr -> upper dst
                const int slo = dlo & 1;
#pragma unroll
                for (int nt = 0; nt < 4; ++nt) {
                    v4f acc = {0.f,0.f,0.f,0.f};
                    acc = __builtin_amdgcn_mfma_f32_16x16x32_bf16(A0.v, w2f[nt*2+0], acc, 0,0,0);
                    acc = __builtin_amdgcn_mfma_f32_16x16x32_bf16(A1.v, w2f[nt*2+1], acc, 0,0,0);
                    int col = nt*16 + c16;
                    float msum = 0.f;
#pragma unroll
                    for (int reg = 0; reg < 4; ++reg) {
                        float v = silu_f(acc[reg] + b2e_v[nt]);
                        tile[(q4*4 + reg)*72 + col] = f2bf(v);
                        msum += v;
                    }
                    bool hi = (q4 >= thr);
                    miacc[nt][slo]     += hi ? 0.f : msum;
                    miacc[nt][slo ^ 1] += hi ? msum : 0.f;
                }
                asm volatile("s_waitcnt lgkmcnt(0)" ::: "memory");
                s8v c0 = *(const s8v*)(tile + c16*72 +      q4*8);
                s8v c1 = *(const s8v*)(tile + c16*72 + 32 + q4*8);
                // cw = silu(m2@Wc1 + cb1) . w2c
                float cwp[4] = {0.f,0.f,0.f,0.f};
#pragma unroll
                for (int nt = 0; nt < 4; ++nt) {
                    v4f acc = {0.f,0.f,0.f,0.f};
                    acc = __builtin_amdgcn_mfma_f32_16x16x32_bf16(c0, wc1f[nt*2+0], acc, 0,0,0);
                    acc = __builtin_amdgcn_mfma_f32_16x16x32_bf16(c1, wc1f[nt*2+1], acc, 0,0,0);
#pragma unroll
                    for (int reg = 0; reg < 4; ++reg)
                        cwp[reg] += silu_f(acc[reg] + cb1_v[nt]) * w2c_v[nt];
                }
#pragma unroll
                for (int reg = 0; reg < 4; ++reg) {
                    float v = cwp[reg];
                    v += __shfl_xor(v, 1); v += __shfl_xor(v, 2);
                    v += __shfl_xor(v, 4); v += __shfl_xor(v, 8);
                    int e = e0g + q4*4 + reg;
                    if (c16 < 3) {
                        int src = __float_as_int(s_emeta[e].y);
                        atomicAdd(&s_shift[src*3 + c16], s_endc[e*3 + c16] * v);
                    }
                }
                // flush completed dsts (dst d complete iff (d+1)*12 <= m*16+16)
                if (m == 0) { flushd(0); }
                else if (m == 1) { flushd(1); }
                else if (m == 2) { flushd(2); flushd(3); }
                else if (m == 3) { flushd(4); }
                else if (m == 4) { flushd(5); }
                else             { flushd(6); flushd(7); }
            }
        }

        // prefetch GEMM1 B-frags BEFORE the barrier (2 nt-sets)
        const int mtA = wave & 1, nt0 = wave >> 1, nt1 = (wave >> 1) + 2;
        s8v bn1[8];
#pragma unroll
        for (int kt = 0; kt < 4; ++kt) {
            bn1[kt]   = *(const s8v*)(wl + 16384 + ((nt0*4+kt)*64 + lane)*8);
            bn1[4+kt] = *(const s8v*)(wl + 16384 + ((nt1*4+kt)*64 + lane)*8);
        }
        __syncthreads();    // B3

        // ---- node GEMM1: wave -> (mtA, nt0) and (mtA, nt1), shared A-frags ----
        {
            s8v aA[4];
#pragma unroll
            for (int kt = 0; kt < 4; ++kt)
                aA[kt] = *(const s8v*)(s_habf + (mtA*16 + c16)*136 + kt*32 + q4*8);
#pragma unroll
            for (int it = 0; it < 2; ++it) {
                int nt = it ? nt1 : nt0;
                int col = nt*16 + c16;
                float nbc = s_nb4[l*64 + col];
                v4f acc = {0.f,0.f,0.f,0.f};
#pragma unroll
                for (int kt = 0; kt < 4; ++kt)
                    acc = __builtin_amdgcn_mfma_f32_16x16x32_bf16(aA[kt], bn1[it*4+kt], acc, 0,0,0);
#pragma unroll
                for (int reg = 0; reg < 4; ++reg) {
                    int row = mtA*16 + q4*4 + reg;
                    s_n1bf[row*72 + col] = f2bf(silu_f(acc[reg] + nbc));
                }
            }
        }
        // prefetch GEMM2 B-frags before B4
        s8v bn2[4];
        bn2[0] = *(const s8v*)(wl + 24576 + ((nt0*2+0)*64 + lane)*8);
        bn2[1] = *(const s8v*)(wl + 24576 + ((nt0*2+1)*64 + lane)*8);
        bn2[2] = *(const s8v*)(wl + 24576 + ((nt1*2+0)*64 + lane)*8);
        bn2[3] = *(const s8v*)(wl + 24576 + ((nt1*2+1)*64 + lane)*8);
        __syncthreads();    // B4

        // ---- node GEMM2: h += n1@Wn2 + b2, two nt sub-tiles, shared A-frags ----
        {
            s8v a0 = *(const s8v*)(s_n1bf + (mtA*16 + c16)*72 +      q4*8);
            s8v a1 = *(const s8v*)(s_n1bf + (mtA*16 + c16)*72 + 32 + q4*8);
#pragma unroll
            for (int it = 0; it < 2; ++it) {
                int nt = it ? nt1 : nt0;
                int col = nt*16 + c16;
                float nb2_v = node_b2[l*64 + col];
                v4f acc = {0.f,0.f,0.f,0.f};
                acc = __builtin_amdgcn_mfma_f32_16x16x32_bf16(a0, bn2[it*2+0], acc, 0,0,0);
                acc = __builtin_amdgcn_mfma_f32_16x16x32_bf16(a1, bn2[it*2+1], acc, 0,0,0);
#pragma unroll
                for (int reg = 0; reg < 4; ++reg) {
                    int row = mtA*16 + q4*4 + reg;
                    float hn = s_h[row*65 + col] + acc[reg] + nb2_v;
                    s_h[row*65 + col] = hn;
                    s_habf[row*136 + col] = f2bf(hn);
                }
            }
        }
        __syncthreads();    // B5
    }

    // ---------------- epilogue ----------------
    if (tid == 0) {
        float a=s_lat[0],b=s_lat[1],cc=s_lat[2];
        float d=s_lat[3],e=s_lat[4],f =s_lat[5];
        float g=s_lat[6],h2=s_lat[7],i2=s_lat[8];
        float A  =  (e*i2 - f*h2);
        float Bm = -(d*i2 - f*g);
        float C  =  (d*h2 - e*g);
        float det = a*A + b*Bm + cc*C;
        float rd = 1.0f/det;
        s_inv[0] = A*rd;
        s_inv[1] = -(b*i2 - cc*h2)*rd;
        s_inv[2] =  (b*f  - cc*e )*rd;
        s_inv[3] = Bm*rd;
        s_inv[4] =  (a*i2 - cc*g )*rd;
        s_inv[5] = -(a*f  - cc*d )*rd;
        s_inv[6] = C*rd;
        s_inv[7] = -(a*h2 - b*g  )*rd;
        s_inv[8] =  (a*e  - b*d  )*rd;
    }
    __syncthreads();
    if (tid < 96) {
        int r = tid/3, j = tid%3;
        float v = s_shift[r*3+0]*s_inv[0*3+j]
                + s_shift[r*3+1]*s_inv[1*3+j]
                + s_shift[r*3+2]*s_inv[2*3+j];
        out[(base + r)*3 + j] = v;
    }
    for (int q = tid; q < 2048; q += 256) {
        int row = q >> 6, colq = q & 63;
        out[NN*3 + base*64 + q] = s_h[row*65 + colq];
    }
}

extern "C" void kernel_launch(void* const* d_in, const int* in_sizes, int n_in,
                              void* d_out, int out_size, void* d_ws, size_t ws_size,
                              hipStream_t stream) {
    unsigned short* wbf = (unsigned short*)d_ws;
    prepack_w<<<(4*WPL/8 + 255)/256, 256, 0, stream>>>(
        (const float*)d_in[12], (const float*)d_in[14], (const float*)d_in[16],
        (const float*)d_in[19], (const float*)d_in[21], wbf);
    crystal_fused<<<NB, 256, 0, stream>>>(
        (const float*)d_in[0],  (const float*)d_in[1],  (const float*)d_in[2],  (const float*)d_in[3],
        (const float*)d_in[6],  (const float*)d_in[7],  (const float*)d_in[8],  (const float*)d_in[9],
        (const float*)d_in[10], (const float*)d_in[11],
        (const float*)d_in[12], (const float*)d_in[13], (const float*)d_in[15],
        (const float*)d_in[17], (const float*)d_in[18],
        (const float*)d_in[19], (const float*)d_in[20], (const float*)d_in[22],
        wbf, (float*)d_out);
}

// Round 13
// 197.273 us; speedup vs baseline: 1.1568x; 1.0172x over previous
//
#include <hip/hip_runtime.h>
#include <hip/hip_bf16.h>
#include <math.h>

#define NB 512
#define NPC 32
#define KNN 12
#define NL 4
#define NN (NB*NPC)
#define WPL 28672   // prepacked bf16 weight elems per layer

typedef float v4f __attribute__((ext_vector_type(4)));
typedef float v2f __attribute__((ext_vector_type(2)));
typedef short s8v __attribute__((ext_vector_type(8)));   // 16 B = 4 VGPRs

// fast silu: ~5 VALU ops (2 transcendental) vs ~10-op exact divide
__device__ __forceinline__ float silu_f(float x) {
    return x * __builtin_amdgcn_rcpf(1.0f + __builtin_amdgcn_exp2f(x * -1.44269504088896341f));
}

// packed-pair silu: muls/adds become v_pk_*_f32 (2 fp32/instr on CDNA4)
__device__ __forceinline__ v2f silu2(v2f x) {
    v2f n = x * -1.44269504088896341f;
    v2f e; e.x = __builtin_amdgcn_exp2f(n.x); e.y = __builtin_amdgcn_exp2f(n.y);
    v2f d = e + 1.0f;
    v2f r; r.x = __builtin_amdgcn_rcpf(d.x); r.y = __builtin_amdgcn_rcpf(d.y);
    return x * r;
}

__device__ __forceinline__ unsigned short f2bf(float x) {
    unsigned u = __float_as_uint(x);
    u += 0x7fffu + ((u >> 16) & 1u);
    return (unsigned short)(u >> 16);
}

// packed 2xfloat -> 2xbf16 in one u32 (v_cvt_pk_bf16_f32)
__device__ __forceinline__ unsigned pk2bf(float a, float b) {
    __hip_bfloat162 t = __float22bfloat162_rn(make_float2(a, b));
    union { __hip_bfloat162 h; unsigned u; } c; c.h = t;
    return c.u;
}
__device__ __forceinline__ unsigned pk2bfu(v2f s) { return pk2bf(s.x, s.y); }

// e/12 for e<384 via magic mul (exact over [0,384))
__device__ __forceinline__ int div12(int e) { return (e * 1366) >> 14; }

// fp32 fallback GEMM (embedding only)
template<int R>
__device__ __forceinline__ void gemm_acc(const float* A, int astride,
                                         const float* __restrict__ Wg,
                                         int K, int lane, float* acc) {
#pragma unroll 2
    for (int kq = 0; kq < (K >> 2); ++kq) {
        float w0 = Wg[(4*kq+0)*64 + lane];
        float w1 = Wg[(4*kq+1)*64 + lane];
        float w2 = Wg[(4*kq+2)*64 + lane];
        float w3 = Wg[(4*kq+3)*64 + lane];
#pragma unroll
        for (int r = 0; r < R; ++r) {
            float4 a = *(const float4*)(A + r*astride + 4*kq);
            acc[r] = fmaf(a.x, w0, acc[r]);
            acc[r] = fmaf(a.y, w1, acc[r]);
            acc[r] = fmaf(a.z, w2, acc[r]);
            acc[r] = fmaf(a.w, w3, acc[r]);
        }
    }
}

// ---------------- prepack (unchanged) ----------------
extern "C" __global__ void prepack_w(const float* __restrict__ edge_w1, const float* __restrict__ edge_w2,
                                     const float* __restrict__ coord_w1, const float* __restrict__ node_w1,
                                     const float* __restrict__ node_w2, unsigned short* __restrict__ wout) {
    int g = blockIdx.x * 256 + threadIdx.x;
    if (g >= 4 * WPL / 8) return;
    int l = (g * 8) / WPL;
    int r = (g * 8) % WPL;
    int base, nKt, mat;
    if      (r < 8192)  { base = 0;     nKt = 2; mat = 0; }
    else if (r < 12288) { base = 8192;  nKt = 2; mat = 1; }
    else if (r < 16384) { base = 12288; nKt = 2; mat = 2; }
    else if (r < 24576) { base = 16384; nKt = 4; mat = 3; }
    else                { base = 24576; nKt = 2; mat = 4; }
    int idx = r - base;
    int lane = (idx >> 3) & 63, t = idx >> 9;
    int kt = t % nKt, nt = t / nKt;
    int k0 = kt*32 + ((lane >> 4) & 3)*8;
    int n  = nt*16 + (lane & 15);
    unsigned short o[8];
#pragma unroll
    for (int j = 0; j < 8; ++j) {
        int k = k0 + j;
        float v;
        if      (mat == 0) v = (n < 64) ? edge_w1[l*193*64 + k*64 + n] : edge_w1[l*193*64 + (64+k)*64 + (n-64)];
        else if (mat == 1) v = edge_w2 [l*4096 + k*64 + n];
        else if (mat == 2) v = coord_w1[l*4096 + k*64 + n];
        else if (mat == 3) v = node_w1 [l*192*64 + k*64 + n];
        else               v = node_w2 [l*4096 + k*64 + n];
        o[j] = f2bf(v);
    }
    *(s8v*)(wout + g*8) = *(s8v*)o;
}

// ---------------- main fused kernel: one block (4 waves) per crystal ----------------
// R13: R12 structure frozen (2x256-thread blocks/CU = TLP cap). VALU diet:
// packed-fp32 (v_pk_*_f32) arithmetic in m1-build / m2 / cw silu paths via
// ext_vector float2; v_cvt_pk_bf16_f32 tile stores; w2f/wc1f/W4 weight loads
// hoisted before step A so L2 latency hides under MFMA.
extern "C" __global__ __launch_bounds__(256, 2)
void crystal_fused(const float* __restrict__ z_nodes, const float* __restrict__ t_in,
                   const float* __restrict__ frac,    const float* __restrict__ lattice,
                   const float* __restrict__ time_w1, const float* __restrict__ time_b1,
                   const float* __restrict__ time_w2, const float* __restrict__ time_b2,
                   const float* __restrict__ emb_w,   const float* __restrict__ emb_b,
                   const float* __restrict__ edge_w1, const float* __restrict__ edge_b1,
                   const float* __restrict__ edge_b2, const float* __restrict__ coord_b1,
                   const float* __restrict__ coord_w2,
                   const float* __restrict__ node_w1, const float* __restrict__ node_b1,
                   const float* __restrict__ node_b2,
                   const unsigned short* __restrict__ wbf,
                   float* __restrict__ out)
{
    __shared__ __align__(16) float s_h[32*65];
    __shared__ __align__(16) unsigned short s_habf[32*136];        // bf16 [h | m_i]
    __shared__ __align__(16) unsigned short s_n1bf[32*72];
    __shared__ __align__(16) float s_hs[32*68];                    // stride 68: rows 16B-aligned
    __shared__ __align__(16) float s_hd[32*68];
    __shared__ __align__(16) unsigned short s_tiles16[8192];       // 16KB: per-wave m2 tiles (4x1152) / dcf / zbuf
    __shared__ float s_dsq[32][33];
    __shared__ float2 s_emeta[384];                                // {dist_sq, src bits}
    __shared__ float s_endc[384*3];
    __shared__ float s_frac[32][3];
    __shared__ float s_lat[9], s_inv[9];
    __shared__ float s_sinu[64], s_t1[128], s_tf[64];
    __shared__ float s_tb4[NL*64], s_nb4[NL*64];                   // per-layer t-terms (prologue)
    __shared__ float s_shift[32*3];

    const int tid  = threadIdx.x;
    const int c    = blockIdx.x;
    const int lane = tid & 63;
    const int wave = tid >> 6;       // 0..3
    const int q4   = lane >> 4;
    const int c16  = lane & 15;
    const int base = c * NPC;

    // ---------------- phase 0 ----------------
    if (tid < 96) {
        ((float*)s_frac)[tid] = frac[base*3 + tid];
    } else if (tid < 105) {
        s_lat[tid-96] = lattice[c*9 + (tid-96)];
    } else if (tid >= 128 && tid < 160) {
        int i = tid - 128;
        float freq = expf((float)i * (-9.210340371976184f / 31.0f));
        float ang  = t_in[c] * freq;
        s_sinu[i]    = sinf(ang);
        s_sinu[i+32] = cosf(ang);
    }
    __syncthreads();

    // ---------------- phase 1: PBC pair distances ----------------
    float* dcf = (float*)s_tiles16;      // [1024][3] = 12KB
    {
        float l00=s_lat[0],l01=s_lat[1],l02=s_lat[2];
        float l10=s_lat[3],l11=s_lat[4],l12=s_lat[5];
        float l20=s_lat[6],l21=s_lat[7],l22=s_lat[8];
        for (int p = tid; p < 1024; p += 256) {
            int i = p >> 5, j = p & 31;
            float dx = s_frac[i][0]-s_frac[j][0];
            float dy = s_frac[i][1]-s_frac[j][1];
            float dz = s_frac[i][2]-s_frac[j][2];
            dx -= rintf(dx); dy -= rintf(dy); dz -= rintf(dz);
            float cx = dx*l00 + dy*l10 + dz*l20;
            float cy = dx*l01 + dy*l11 + dz*l21;
            float cz = dx*l02 + dy*l12 + dz*l22;
            float dd = cx*cx + cy*cy + cz*cz;
            s_dsq[i][j] = (i==j) ? 3.0e38f : dd;
            dcf[p*3+0]=cx; dcf[p*3+1]=cy; dcf[p*3+2]=cz;
        }
    }
    __syncthreads();

    // ---------------- phase 2: KNN (wave0 lanes<32) || time-MLP L1 (waves 2,3) ----------------
    if (tid < 32) {
        int i = tid;
        for (int k = 0; k < KNN; ++k) {
            float best = 3.9e38f; int bj = 0;
            for (int j = 0; j < 32; ++j) {
                float v = s_dsq[i][j];
                if (v < best) { best = v; bj = j; }
            }
            s_dsq[i][bj] = 3.9e38f;
            int e = i*KNN + k;
            s_emeta[e] = make_float2(best, __int_as_float(bj));
            int p = (i<<5) + bj;
            s_endc[e*3+0] = dcf[p*3+0];
            s_endc[e*3+1] = dcf[p*3+1];
            s_endc[e*3+2] = dcf[p*3+2];
        }
    } else if (tid >= 128) {
        int jj = tid - 128;
        float p0 = time_b1[jj], p1=0.f, p2=0.f, p3=0.f;
        for (int k = 0; k < 64; k += 4) {
            p0 = fmaf(s_sinu[k+0], time_w1[(k+0)*128+jj], p0);
            p1 = fmaf(s_sinu[k+1], time_w1[(k+1)*128+jj], p1);
            p2 = fmaf(s_sinu[k+2], time_w1[(k+2)*128+jj], p2);
            p3 = fmaf(s_sinu[k+3], time_w1[(k+3)*128+jj], p3);
        }
        s_t1[jj] = silu_f((p0+p1) + (p2+p3));
    }
    __syncthreads();

    // ---------------- phase 3: t_feat ; zero shift ----------------
    if (tid < 64) {
        float p0=time_b2[tid],p1=0.f,p2=0.f,p3=0.f;
        for (int k = 0; k < 128; k += 4) {
            p0 = fmaf(s_t1[k+0], time_w2[(k+0)*64+tid], p0);
            p1 = fmaf(s_t1[k+1], time_w2[(k+1)*64+tid], p1);
            p2 = fmaf(s_t1[k+2], time_w2[(k+2)*64+tid], p2);
            p3 = fmaf(s_t1[k+3], time_w2[(k+3)*64+tid], p3);
        }
        s_tf[tid] = (p0+p1) + (p2+p3);
    } else if (tid < 160) {
        s_shift[tid-64] = 0.0f;
    }
    __syncthreads();

    // ---------------- phase 4: z staging + ALL-layer tb/nb GEMVs (2 tasks/wave) ----------------
    float* zbuf = (float*)s_tiles16;     // [32][128] = 16KB
    for (int q = tid; q < 4096; q += 256) zbuf[q] = z_nodes[base*128 + q];
#pragma unroll
    for (int it = 0; it < 2; ++it) {
        int t = wave + it*4;
        int lt = t >> 1, kind = t & 1;
        const float* Wt = kind ? (node_w1 + lt*192*64 + 128*64) : (edge_w1 + lt*193*64 + 129*64);
        const float* bb = kind ? (node_b1 + lt*64) : (edge_b1 + lt*64);
        float p0 = bb[lane], p1=0.f, p2=0.f, p3=0.f;
        for (int k = 0; k < 64; k += 4) {
            p0 = fmaf(s_tf[k+0], Wt[(k+0)*64 + lane], p0);
            p1 = fmaf(s_tf[k+1], Wt[(k+1)*64 + lane], p1);
            p2 = fmaf(s_tf[k+2], Wt[(k+2)*64 + lane], p2);
            p3 = fmaf(s_tf[k+3], Wt[(k+3)*64 + lane], p3);
        }
        float v = (p0+p1) + (p2+p3);
        if (kind) s_nb4[lt*64 + lane] = v;
        else      s_tb4[lt*64 + lane] = v;
    }
    __syncthreads();

    // ---------------- phase 5: node embedding (8 rows/wave) ----------------
    {
        float acc[8];
#pragma unroll
        for (int r = 0; r < 8; ++r) acc[r] = emb_b[lane];
        gemm_acc<8>(zbuf + (wave*8)*128, 128, emb_w, 128, lane, acc);
#pragma unroll
        for (int r = 0; r < 8; ++r) {
            int row = wave*8 + r;
            s_h[row*65 + lane] = acc[r];
            s_habf[row*136 + lane] = f2bf(acc[r]);
        }
    }
    __syncthreads();    // habf ready for layer 0 step A

    // ---------------- EGNN layers ----------------
    for (int l = 0; l < NL; ++l) {
        const unsigned short* wl = wbf + l*WPL;
        const float* w1row = edge_w1 + l*193*64 + 128*64;   // dist^2 weight row
        float b2e_v[4], cb1_v[4], w2c_v[4];
#pragma unroll
        for (int nt = 0; nt < 4; ++nt) {
            b2e_v[nt] = edge_b2 [l*64 + nt*16 + c16];
            cb1_v[nt] = coord_b1[l*64 + nt*16 + c16];
            w2c_v[nt] = coord_w2[l*64 + nt*16 + c16];
        }

        // hoisted edge-phase weights: issue global loads early, use after step A
        s8v w2f[8], wc1f[8];
#pragma unroll
        for (int nt = 0; nt < 4; ++nt)
#pragma unroll
            for (int kt = 0; kt < 2; ++kt) {
                w2f [nt*2+kt] = *(const s8v*)(wl +  8192 + ((nt*2+kt)*64 + lane)*8);
                wc1f[nt*2+kt] = *(const s8v*)(wl + 12288 + ((nt*2+kt)*64 + lane)*8);
            }
        union F4 { float4 v; float f[4]; };
        F4 W4[4];
        W4[0].v = *(const float4*)(w1row + q4*8);
        W4[1].v = *(const float4*)(w1row + q4*8 + 4);
        W4[2].v = *(const float4*)(w1row + 32 + q4*8);
        W4[3].v = *(const float4*)(w1row + 32 + q4*8 + 4);

        // ---- step A: wave w -> hs ntile w AND hd ntile w (shared A-frags) ----
        {
            s8v a[2][2];
#pragma unroll
            for (int mt = 0; mt < 2; ++mt)
#pragma unroll
                for (int kt = 0; kt < 2; ++kt)
                    a[mt][kt] = *(const s8v*)(s_habf + (mt*16 + c16)*136 + kt*32 + q4*8);
            v4f accS[2] = {{0.f,0.f,0.f,0.f},{0.f,0.f,0.f,0.f}};
            v4f accD[2] = {{0.f,0.f,0.f,0.f},{0.f,0.f,0.f,0.f}};
#pragma unroll
            for (int kt = 0; kt < 2; ++kt) {
                s8v bS = *(const s8v*)(wl + ((wave*2+kt)*64 + lane)*8);
                s8v bD = *(const s8v*)(wl + (((wave+4)*2+kt)*64 + lane)*8);
#pragma unroll
                for (int mt = 0; mt < 2; ++mt) {
                    accS[mt] = __builtin_amdgcn_mfma_f32_16x16x32_bf16(a[mt][kt], bS, accS[mt], 0, 0, 0);
                    accD[mt] = __builtin_amdgcn_mfma_f32_16x16x32_bf16(a[mt][kt], bD, accD[mt], 0, 0, 0);
                }
            }
            int col = wave*16 + c16;
            float tbv = s_tb4[l*64 + col];
#pragma unroll
            for (int mt = 0; mt < 2; ++mt)
#pragma unroll
                for (int reg = 0; reg < 4; ++reg) {
                    int row = mt*16 + q4*4 + reg;
                    s_hs[row*68 + col] = accS[mt][reg];
                    s_hd[row*68 + col] = accD[mt][reg] + tbv;
                }
        }
        __syncthreads();    // B2

        // ---- edge phase: wave owns 96 edges (dsts wave*8..+7), 6 tiles of 16 ----
        {
            unsigned short* tile = s_tiles16 + wave*1152;
            float miacc[4][2];   // rolling 2-slot window (slot = dst&1)
#pragma unroll
            for (int a2 = 0; a2 < 4; ++a2) { miacc[a2][0] = 0.f; miacc[a2][1] = 0.f; }

            auto flushd = [&](int d) {
                int s = d & 1;
#pragma unroll
                for (int nt = 0; nt < 4; ++nt) {
                    float v = miacc[nt][s];
                    v += __shfl_xor(v, 16);
                    v += __shfl_xor(v, 32);
                    s_habf[(wave*8 + d)*136 + 64 + nt*16 + c16] = f2bf(v);
                    miacc[nt][s] = 0.f;
                }
            };

            // all 6 tiles' edge meta upfront
            float2 me0 = s_emeta[wave*96 +  0 + c16];
            float2 me1 = s_emeta[wave*96 + 16 + c16];
            float2 me2 = s_emeta[wave*96 + 32 + c16];
            float2 me3 = s_emeta[wave*96 + 48 + c16];
            float2 me4 = s_emeta[wave*96 + 64 + c16];
            float2 me5 = s_emeta[wave*96 + 80 + c16];

            // preload tile 0 rows
            F4 H[4], G[4];
            {
                int srcn = __float_as_int(me0.y);
                int dstn = div12(wave*96 + c16);
                const float* hsr = s_hs + srcn*68 + q4*8;
                const float* hdr = s_hd + dstn*68 + q4*8;
                H[0].v = *(const float4*)(hsr);      H[1].v = *(const float4*)(hsr+4);
                H[2].v = *(const float4*)(hsr+32);   H[3].v = *(const float4*)(hsr+36);
                G[0].v = *(const float4*)(hdr);      G[1].v = *(const float4*)(hdr+4);
                G[2].v = *(const float4*)(hdr+32);   G[3].v = *(const float4*)(hdr+36);
            }

#pragma unroll
            for (int m = 0; m < 6; ++m) {
                const int e0g = wave*96 + m*16;
                const float dq = (m==0) ? me0.x : (m==1) ? me1.x : (m==2) ? me2.x
                               : (m==3) ? me3.x : (m==4) ? me4.x : me5.x;
                // build A-frags from preloaded H/G — packed-pair math
                union S8 { s8v v; unsigned u[4]; } A0, A1;
#pragma unroll
                for (int g2 = 0; g2 < 4; ++g2) {
                    v2f h0 = {H[g2].f[0], H[g2].f[1]}, h1 = {H[g2].f[2], H[g2].f[3]};
                    v2f g0 = {G[g2].f[0], G[g2].f[1]}, g1 = {G[g2].f[2], G[g2].f[3]};
                    v2f w0 = {W4[g2].f[0], W4[g2].f[1]}, w1 = {W4[g2].f[2], W4[g2].f[3]};
                    v2f t0 = h0 + g0 + w0 * dq;
                    v2f t1 = h1 + g1 + w1 * dq;
                    unsigned lo  = pk2bfu(silu2(t0));
                    unsigned hi2 = pk2bfu(silu2(t1));
                    if (g2 < 2) { A0.u[g2*2] = lo; A0.u[g2*2+1] = hi2; }
                    else        { A1.u[(g2-2)*2] = lo; A1.u[(g2-2)*2+1] = hi2; }
                }
                // prefetch tile m+1 rows (hides under m2/cw below)
                if (m < 5) {
                    float2 men = (m==0) ? me1 : (m==1) ? me2 : (m==2) ? me3
                               : (m==3) ? me4 : me5;
                    int srcn = __float_as_int(men.y);
                    int dstn = div12(e0g + 16 + c16);
                    const float* hsr = s_hs + srcn*68 + q4*8;
                    const float* hdr = s_hd + dstn*68 + q4*8;
                    H[0].v = *(const float4*)(hsr);      H[1].v = *(const float4*)(hsr+4);
                    H[2].v = *(const float4*)(hsr+32);   H[3].v = *(const float4*)(hsr+36);
                    G[0].v = *(const float4*)(hdr);      G[1].v = *(const float4*)(hdr+4);
                    G[2].v = *(const float4*)(hdr+32);   G[3].v = *(const float4*)(hdr+36);
                }

                // m2 = silu(m1@W2 + b2): cached w2f; mi into rolling slots
                const int dlo = (m < 3) ? m : m + 1;           // local dst ids {dlo, dlo+1}
                const int thr = 3 - (m % 3);                   // q4>=thr -> upper dst
                const int slo = dlo & 1;
#pragma unroll
                for (int nt = 0; nt < 4; ++nt) {
                    v4f acc = {0.f,0.f,0.f,0.f};
                    acc = __builtin_amdgcn_mfma_f32_16x16x32_bf16(A0.v, w2f[nt*2+0], acc, 0,0,0);
                    acc = __builtin_amdgcn_mfma_f32_16x16x32_bf16(A1.v, w2f[nt*2+1], acc, 0,0,0);
                    int col = nt*16 + c16;
                    v2f z01 = {acc[0] + b2e_v[nt], acc[1] + b2e_v[nt]};
                    v2f z23 = {acc[2] + b2e_v[nt], acc[3] + b2e_v[nt]};
                    v2f s01 = silu2(z01), s23 = silu2(z23);
                    unsigned p01 = pk2bfu(s01), p23 = pk2bfu(s23);
                    tile[(q4*4 + 0)*72 + col] = (unsigned short)p01;
                    tile[(q4*4 + 1)*72 + col] = (unsigned short)(p01 >> 16);
                    tile[(q4*4 + 2)*72 + col] = (unsigned short)p23;
                    tile[(q4*4 + 3)*72 + col] = (unsigned short)(p23 >> 16);
                    float msum = (s01.x + s01.y) + (s23.x + s23.y);
                    bool hi = (q4 >= thr);
                    miacc[nt][slo]     += hi ? 0.f : msum;
                    miacc[nt][slo ^ 1] += hi ? msum : 0.f;
                }
                asm volatile("s_waitcnt lgkmcnt(0)" ::: "memory");
                s8v c0 = *(const s8v*)(tile + c16*72 +      q4*8);
                s8v c1 = *(const s8v*)(tile + c16*72 + 32 + q4*8);
                // cw = silu(m2@Wc1 + cb1) . w2c — packed pairs (regs stay separate comps)
                v2f cwp01 = {0.f, 0.f}, cwp23 = {0.f, 0.f};
#pragma unroll
                for (int nt = 0; nt < 4; ++nt) {
                    v4f acc = {0.f,0.f,0.f,0.f};
                    acc = __builtin_amdgcn_mfma_f32_16x16x32_bf16(c0, wc1f[nt*2+0], acc, 0,0,0);
                    acc = __builtin_amdgcn_mfma_f32_16x16x32_bf16(c1, wc1f[nt*2+1], acc, 0,0,0);
                    v2f z01 = {acc[0] + cb1_v[nt], acc[1] + cb1_v[nt]};
                    v2f z23 = {acc[2] + cb1_v[nt], acc[3] + cb1_v[nt]};
                    cwp01 += silu2(z01) * w2c_v[nt];
                    cwp23 += silu2(z23) * w2c_v[nt];
                }
                float cwp[4] = {cwp01.x, cwp01.y, cwp23.x, cwp23.y};
#pragma unroll
                for (int reg = 0; reg < 4; ++reg) {
                    float v = cwp[reg];
                    v += __shfl_xor(v, 1); v += __shfl_xor(v, 2);
                    v += __shfl_xor(v, 4); v += __shfl_xor(v, 8);
                    int e = e0g + q4*4 + reg;
                    if (c16 < 3) {
                        int src = __float_as_int(s_emeta[e].y);
                        atomicAdd(&s_shift[src*3 + c16], s_endc[e*3 + c16] * v);
                    }
                }
                // flush completed dsts (dst d complete iff (d+1)*12 <= m*16+16)
                if (m == 0) { flushd(0); }
                else if (m == 1) { flushd(1); }
                else if (m == 2) { flushd(2); flushd(3); }
                else if (m == 3) { flushd(4); }
                else if (m == 4) { flushd(5); }
                else             { flushd(6); flushd(7); }
            }
        }

        // prefetch GEMM1 B-frags BEFORE the barrier (2 nt-sets)
        const int mtA = wave & 1, nt0 = wave >> 1, nt1 = (wave >> 1) + 2;
        s8v bn1[8];
#pragma unroll
        for (int kt = 0; kt < 4; ++kt) {
            bn1[kt]   = *(const s8v*)(wl + 16384 + ((nt0*4+kt)*64 + lane)*8);
            bn1[4+kt] = *(const s8v*)(wl + 16384 + ((nt1*4+kt)*64 + lane)*8);
        }
        __syncthreads();    // B3

        // ---- node GEMM1: wave -> (mtA, nt0) and (mtA, nt1), shared A-frags ----
        {
            s8v aA[4];
#pragma unroll
            for (int kt = 0; kt < 4; ++kt)
                aA[kt] = *(const s8v*)(s_habf + (mtA*16 + c16)*136 + kt*32 + q4*8);
#pragma unroll
            for (int it = 0; it < 2; ++it) {
                int nt = it ? nt1 : nt0;
                int col = nt*16 + c16;
                float nbc = s_nb4[l*64 + col];
                v4f acc = {0.f,0.f,0.f,0.f};
#pragma unroll
                for (int kt = 0; kt < 4; ++kt)
                    acc = __builtin_amdgcn_mfma_f32_16x16x32_bf16(aA[kt], bn1[it*4+kt], acc, 0,0,0);
                v2f z01 = {acc[0] + nbc, acc[1] + nbc};
                v2f z23 = {acc[2] + nbc, acc[3] + nbc};
                unsigned p01 = pk2bfu(silu2(z01)), p23 = pk2bfu(silu2(z23));
                int r0 = mtA*16 + q4*4;
                s_n1bf[(r0+0)*72 + col] = (unsigned short)p01;
                s_n1bf[(r0+1)*72 + col] = (unsigned short)(p01 >> 16);
                s_n1bf[(r0+2)*72 + col] = (unsigned short)p23;
                s_n1bf[(r0+3)*72 + col] = (unsigned short)(p23 >> 16);
            }
        }
        // prefetch GEMM2 B-frags before B4
        s8v bn2[4];
        bn2[0] = *(const s8v*)(wl + 24576 + ((nt0*2+0)*64 + lane)*8);
        bn2[1] = *(const s8v*)(wl + 24576 + ((nt0*2+1)*64 + lane)*8);
        bn2[2] = *(const s8v*)(wl + 24576 + ((nt1*2+0)*64 + lane)*8);
        bn2[3] = *(const s8v*)(wl + 24576 + ((nt1*2+1)*64 + lane)*8);
        __syncthreads();    // B4

        // ---- node GEMM2: h += n1@Wn2 + b2, two nt sub-tiles, shared A-frags ----
        {
            s8v a0 = *(const s8v*)(s_n1bf + (mtA*16 + c16)*72 +      q4*8);
            s8v a1 = *(const s8v*)(s_n1bf + (mtA*16 + c16)*72 + 32 + q4*8);
#pragma unroll
            for (int it = 0; it < 2; ++it) {
                int nt = it ? nt1 : nt0;
                int col = nt*16 + c16;
                float nb2_v = node_b2[l*64 + col];
                v4f acc = {0.f,0.f,0.f,0.f};
                acc = __builtin_amdgcn_mfma_f32_16x16x32_bf16(a0, bn2[it*2+0], acc, 0,0,0);
                acc = __builtin_amdgcn_mfma_f32_16x16x32_bf16(a1, bn2[it*2+1], acc, 0,0,0);
#pragma unroll
                for (int reg = 0; reg < 4; ++reg) {
                    int row = mtA*16 + q4*4 + reg;
                    float hn = s_h[row*65 + col] + acc[reg] + nb2_v;
                    s_h[row*65 + col] = hn;
                    s_habf[row*136 + col] = f2bf(hn);
                }
            }
        }
        __syncthreads();    // B5
    }

    // ---------------- epilogue ----------------
    if (tid == 0) {
        float a=s_lat[0],b=s_lat[1],cc=s_lat[2];
        float d=s_lat[3],e=s_lat[4],f =s_lat[5];
        float g=s_lat[6],h2=s_lat[7],i2=s_lat[8];
        float A  =  (e*i2 - f*h2);
        float Bm = -(d*i2 - f*g);
        float C  =  (d*h2 - e*g);
        float det = a*A + b*Bm + cc*C;
        float rd = 1.0f/det;
        s_inv[0] = A*rd;
        s_inv[1] = -(b*i2 - cc*h2)*rd;
        s_inv[2] =  (b*f  - cc*e )*rd;
        s_inv[3] = Bm*rd;
        s_inv[4] =  (a*i2 - cc*g )*rd;
        s_inv[5] = -(a*f  - cc*d )*rd;
        s_inv[6] = C*rd;
        s_inv[7] = -(a*h2 - b*g  )*rd;
        s_inv[8] =  (a*e  - b*d  )*rd;
    }
    __syncthreads();
    if (tid < 96) {
        int r = tid/3, j = tid%3;
        float v = s_shift[r*3+0]*s_inv[0*3+j]
                + s_shift[r*3+1]*s_inv[1*3+j]
                + s_shift[r*3+2]*s_inv[2*3+j];
        out[(base + r)*3 + j] = v;
    }
    for (int q = tid; q < 2048; q += 256) {
        int row = q >> 6, colq = q & 63;
        out[NN*3 + base*64 + q] = s_h[row*65 + colq];
    }
}

extern "C" void kernel_launch(void* const* d_in, const int* in_sizes, int n_in,
                              void* d_out, int out_size, void* d_ws, size_t ws_size,
                              hipStream_t stream) {
    unsigned short* wbf = (unsigned short*)d_ws;
    prepack_w<<<(4*WPL/8 + 255)/256, 256, 0, stream>>>(
        (const float*)d_in[12], (const float*)d_in[14], (const float*)d_in[16],
        (const float*)d_in[19], (const float*)d_in[21], wbf);
    crystal_fused<<<NB, 256, 0, stream>>>(
        (const float*)d_in[0],  (const float*)d_in[1],  (const float*)d_in[2],  (const float*)d_in[3],
        (const float*)d_in[6],  (const float*)d_in[7],  (const float*)d_in[8],  (const float*)d_in[9],
        (const float*)d_in[10], (const float*)d_in[11],
        (const float*)d_in[12], (const float*)d_in[13], (const float*)d_in[15],
        (const float*)d_in[17], (const float*)d_in[18],
        (const float*)d_in[19], (const float*)d_in[20], (const float*)d_in[22],
        wbf, (float*)d_out);
}